// Round 6
// baseline (300.508 us; speedup 1.0000x reference)
//
#include <hip/hip_runtime.h>
#include <hip/hip_bf16.h>

typedef unsigned short u16;
typedef short short8 __attribute__((ext_vector_type(8)));
typedef float f32x4 __attribute__((ext_vector_type(4)));
typedef float f32x16 __attribute__((ext_vector_type(16)));
typedef unsigned uint32x4 __attribute__((ext_vector_type(4)));

#define N_EMBD   1024
#define N_HEADS  16
#define HEAD_DIM 64
#define PRIV     48
#define SEQ_T    2048
#define BATCH    4
#define M_ROWS   (BATCH*SEQ_T)   // 8192
#define PNS      2816            // [share 16 | q 768 | k 768 | v 1024] = 2576 -> 11*256
#define NTILES   (SEQ_T/64)      // 32
#define NT_K     16              // K=1024 / BK=64

#if __has_builtin(__builtin_amdgcn_exp2f)
#define EXP2(x) __builtin_amdgcn_exp2f(x)
#else
#define EXP2(x) exp2f(x)
#endif

#if __has_builtin(__builtin_amdgcn_global_load_lds)
#define HAVE_GLL 1
#else
#define HAVE_GLL 0
#endif

__device__ __forceinline__ u16 f2bf(float f) {
  __hip_bfloat16 h = __float2bfloat16(f);
  return *reinterpret_cast<u16*>(&h);
}
__device__ __forceinline__ float bf2f(u16 s) {
  __hip_bfloat16 h;
  *reinterpret_cast<u16*>(&h) = s;
  return __bfloat162float(h);
}
__device__ __forceinline__ float loadv(const void* p, size_t i, int isf32) {
  return isf32 ? ((const float*)p)[i] : bf2f(((const u16*)p)[i]);
}
__device__ __forceinline__ u16 truncbf(float f) {
  unsigned u = __builtin_bit_cast(unsigned, f);
  return (u16)(u >> 16);
}
#if HAVE_GLL
__device__ __forceinline__ void gload_lds16(const u16* g, u16* l) {
  __builtin_amdgcn_global_load_lds(
      (const __attribute__((address_space(1))) void*)g,
      (__attribute__((address_space(3))) void*)l, 16, 0, 0);
}
#endif

// ---------------------------------------------------------------------------
// Dtype detector (1 = f32 inputs).
// ---------------------------------------------------------------------------
__global__ __launch_bounds__(256) void detect_kernel(const u16* __restrict__ x,
                                                     int* __restrict__ flag) {
  __shared__ int cnt;
  if (threadIdx.x == 0) cnt = 0;
  __syncthreads();
  u16 v = x[2 * threadIdx.x];
  int e = (v >> 7) & 0xFF;
  int junk = (e >= 0xC0 || (e != 0 && e <= 0x30)) ? 1 : 0;
  if (junk) atomicAdd(&cnt, 1);
  __syncthreads();
  if (threadIdx.x == 0) *flag = (cnt > 16) ? 1 : 0;
}

// ---------------------------------------------------------------------------
// Transposing pack (weights -> [n][k] bf16) + z=5 slice does zero-pad + biases.
// ---------------------------------------------------------------------------
__global__ __launch_bounds__(256) void pack_t_kernel(
    const void* __restrict__ Wsh, const void* __restrict__ Wq,
    const void* __restrict__ Wk,  const void* __restrict__ Wv,
    const void* __restrict__ Wo,
    const void* __restrict__ bsh, const void* __restrict__ bq,
    const void* __restrict__ bk,  const void* __restrict__ bv,
    const void* __restrict__ bo,
    u16* __restrict__ Wcat, u16* __restrict__ Woc,
    u16* __restrict__ bcat, u16* __restrict__ boc,
    const int* __restrict__ flagp)
{
  const int f = *flagp;
  if (blockIdx.z == 5) {  // pad + biases
    const int flat = blockIdx.y * 16 + blockIdx.x;
    const int padN = (PNS - 2576) * 1024;
    for (int i = flat * 256 + threadIdx.x; i < padN; i += 256 * 256)
      Wcat[(size_t)2576 * 1024 + i] = 0;
    if (flat == 0) {
      for (int c = threadIdx.x; c < PNS; c += 256) {
        float v = 0.f;
        if (c < 16)        v = loadv(bsh, c, f);
        else if (c < 784)  v = loadv(bq, c - 16, f);
        else if (c < 1552) v = loadv(bk, c - 784, f);
        else if (c < 2576) v = loadv(bv, c - 1552, f);
        bcat[c] = f2bf(v);
      }
    } else if (flat == 1) {
      for (int c = threadIdx.x; c < N_EMBD; c += 256)
        boc[c] = f2bf(loadv(bo, c, f));
    }
    return;
  }
  const void* src; u16* dst; int N, rowOff;
  switch (blockIdx.z) {
    case 0: src = Wsh; dst = Wcat; N = 16;   rowOff = 0;    break;
    case 1: src = Wq;  dst = Wcat; N = 768;  rowOff = 16;   break;
    case 2: src = Wk;  dst = Wcat; N = 768;  rowOff = 784;  break;
    case 3: src = Wv;  dst = Wcat; N = 1024; rowOff = 1552; break;
    default:src = Wo;  dst = Woc;  N = 1024; rowOff = 0;    break;
  }
  const int n0 = blockIdx.x * 64;
  if (n0 >= N) return;
  const int k0 = blockIdx.y * 64;
  __shared__ u16 t[64][65];
  const int tx = threadIdx.x & 63, ty = threadIdx.x >> 6;
#pragma unroll
  for (int rr = 0; rr < 16; rr++) {
    int k = k0 + ty * 16 + rr;
    int n = n0 + tx;
    float v = (n < N) ? loadv(src, (size_t)k * N + n, f) : 0.f;
    t[ty * 16 + rr][tx] = f2bf(v);
  }
  __syncthreads();
#pragma unroll
  for (int rr = 0; rr < 16; rr++) {
    int n = ty * 16 + rr;
    if (n0 + n < N)
      dst[(size_t)(rowOff + n0 + n) * 1024 + k0 + tx] = t[tx][n];
  }
}

// ---------------------------------------------------------------------------
// x (f32 or bf16 per flag) -> Xb bf16 [8192][1024]. 8 elems/thread.
// ---------------------------------------------------------------------------
__global__ __launch_bounds__(256) void xbf_kernel(const void* __restrict__ x,
                                                  u16* __restrict__ Xb,
                                                  const int* __restrict__ flagp) {
  const int f = *flagp;
  const size_t i = (size_t)blockIdx.x * 256 + threadIdx.x;
  if (f) {
    const float4* p = (const float4*)x;
    float4 a = p[i * 2], b = p[i * 2 + 1];
    u16 t[8] = {f2bf(a.x), f2bf(a.y), f2bf(a.z), f2bf(a.w),
                f2bf(b.x), f2bf(b.y), f2bf(b.z), f2bf(b.w)};
    *(uint4*)&Xb[i * 8] = *(const uint4*)t;
  } else {
    *(uint4*)&Xb[i * 8] = ((const uint4*)x)[i];
  }
}

// ---------------------------------------------------------------------------
// 8-wave deep-pipelined bf16 GEMM: C(MxN) = A(MxK=1024) @ Bt(NxK)^T + bias.
// Tile BM=128 x BN=256, BK=64. 512 thr = 8 waves (2M x 4N), 64x64 out/wave.
// Triple-buffered LDS; counted vmcnt(6) schedule (T3+T4); T2 XOR swizzle;
// T5 setprio. Unchanged since round 1.
// ---------------------------------------------------------------------------
__global__ __launch_bounds__(512, 2) void gemm8p_kernel(
    const u16* __restrict__ A,    // [M][1024] bf16
    const u16* __restrict__ Bt,   // [N][1024] bf16
    const u16* __restrict__ bias, // [N] bf16
    void* __restrict__ C, int ldc, int Mtiles,
    const int* __restrict__ flagp, int c_dyn)
{
  __shared__ __align__(16) u16 smem[73728];   // 147456 B
  u16* const As = smem;                       // 3 x [128*64]
  u16* const Bs = smem + 3 * 8192;            // 3 x [256*64]

  const bool cf32 = (c_dyn != 0) && (*flagp != 0);

  const int tid  = threadIdx.x;
  const int lane = tid & 63;
  const int w    = tid >> 6;
  const int quad = lane >> 4, l16 = lane & 15;
  const int wm   = w >> 2, wn = w & 3;

  const int nwg = gridDim.x;
  const int wg  = (blockIdx.x & 7) * (nwg >> 3) + (blockIdx.x >> 3);
  const int mb  = wg % Mtiles, nb = wg / Mtiles;
  const int m0  = mb * 128, n0 = nb * 256;

  int ldsA[2]; size_t glA[2];
  int ldsB[2][2]; size_t glB[2][2];
#pragma unroll
  for (int rd = 0; rd < 2; rd++) {
    int j = tid + rd * 512, rp = j >> 3, s = j & 7;
    int cl = (s ^ (rp & 7)) * 8;
    ldsA[rd] = rp * 64 + s * 8;
    glA[rd]  = (size_t)(m0 + rp) * 1024 + cl;
#pragma unroll
    for (int nh = 0; nh < 2; nh++) {
      int cc = (rp & 31) + nh * 32 + (rp >> 5) * 64;
      ldsB[nh][rd] = cc * 64 + s * 8;
      glB[nh][rd]  = (size_t)(n0 + cc) * 1024 + cl;
    }
  }

#if HAVE_GLL
#define G8(g, l) gload_lds16((g), (l))
#else
#define G8(g, l) (*(uint4*)(l) = *(const uint4*)(g))
#endif
#define STG_A(t, bf)                                                       \
  if ((t) < NT_K) {                                                        \
    _Pragma("unroll") for (int rd = 0; rd < 2; rd++)                       \
      G8(A + glA[rd] + (t) * 64, As + (bf) * 8192 + ldsA[rd]);             \
  }
#define STG_B(nh, t, bf)                                                   \
  if ((t) < NT_K) {                                                        \
    _Pragma("unroll") for (int rd = 0; rd < 2; rd++)                       \
      G8(Bt + glB[nh][rd] + (t) * 64, Bs + (bf) * 16384 + ldsB[nh][rd]);   \
  }

  const int ck0  = ((quad)     ^ (l16 & 7)) * 8;
  const int ck1  = ((4 + quad) ^ (l16 & 7)) * 8;
  const int arow = (wm * 64 + l16) * 64;
  const int brow = (wn * 64 + l16) * 64;

  f32x4 acc[4][4];
#pragma unroll
  for (int i = 0; i < 4; i++)
#pragma unroll
    for (int j = 0; j < 4; j++) acc[i][j] = (f32x4){0.f, 0.f, 0.f, 0.f};

  short8 af[4][2], bA[2][2], bB[2][2];

#define READ_A(cur)                                                        \
  { const u16* pa = As + (cur) * 8192 + arow;                              \
    _Pragma("unroll") for (int m = 0; m < 4; m++) {                        \
      af[m][0] = *(const short8*)(pa + m * 1024 + ck0);                    \
      af[m][1] = *(const short8*)(pa + m * 1024 + ck1); } }
#define READ_B(dst, nh, cur)                                               \
  { const u16* pb = Bs + (cur) * 16384 + brow + (nh) * 2048;               \
    _Pragma("unroll") for (int n = 0; n < 2; n++) {                        \
      dst[n][0] = *(const short8*)(pb + n * 1024 + ck0);                   \
      dst[n][1] = *(const short8*)(pb + n * 1024 + ck1); } }
#define MM16(bfr, nh)                                                      \
  __builtin_amdgcn_s_setprio(1);                                           \
  _Pragma("unroll") for (int m = 0; m < 4; m++)                            \
    _Pragma("unroll") for (int n = 0; n < 2; n++) {                        \
      acc[m][(nh)*2+n] = __builtin_amdgcn_mfma_f32_16x16x32_bf16(          \
          af[m][0], bfr[n][0], acc[m][(nh)*2+n], 0, 0, 0);                 \
      acc[m][(nh)*2+n] = __builtin_amdgcn_mfma_f32_16x16x32_bf16(          \
          af[m][1], bfr[n][1], acc[m][(nh)*2+n], 0, 0, 0); }               \
  __builtin_amdgcn_s_setprio(0);
#define BARR { __builtin_amdgcn_s_barrier(); __builtin_amdgcn_sched_barrier(0); }

  STG_A(0, 0); STG_B(1, 0, 0); STG_B(0, 0, 0);
  STG_A(1, 1); STG_B(1, 1, 1); STG_B(0, 1, 1);
  asm volatile("s_waitcnt vmcnt(6)");
  BARR;

#pragma unroll
  for (int kt = 0; kt < NT_K; kt++) {
    const int cur = kt % 3;
    const int stb = (kt + 2) % 3;
    READ_A(cur); READ_B(bA, 0, cur);
    STG_A(kt + 2, stb); STG_B(1, kt + 2, stb);
    BARR;
    MM16(bA, 0);
    BARR;
    READ_B(bB, 1, cur);
    STG_B(0, kt + 2, stb);
    BARR;
    MM16(bB, 1);
    if (kt < NT_K - 2)       { asm volatile("s_waitcnt vmcnt(6)"); }
    else if (kt == NT_K - 2) { asm volatile("s_waitcnt vmcnt(0)"); }
    BARR;
  }
#undef STG_A
#undef STG_B
#undef READ_A
#undef READ_B
#undef MM16
#undef BARR
#undef G8

  float bvv[4];
#pragma unroll
  for (int ni = 0; ni < 4; ni++)
    bvv[ni] = bf2f(bias[n0 + wn * 64 + ni * 16 + l16]);

  if (!cf32) {
    u16* cs = smem + w * 4096;
#pragma unroll
    for (int m = 0; m < 4; m++)
#pragma unroll
      for (int ni = 0; ni < 4; ni++)
#pragma unroll
        for (int r = 0; r < 4; r++) {
          int row = m * 16 + quad * 4 + r;
          int ch  = ((ni * 2 + (l16 >> 3)) ^ (row & 7)) * 8 + (l16 & 7);
          cs[row * 64 + ch] = f2bf(acc[m][ni][r] + bvv[ni]);
        }
    u16* Cb = (u16*)C;
#pragma unroll
    for (int i = 0; i < 8; i++) {
      int ch = lane + i * 64;
      int rr = ch >> 3, cc = ch & 7;
      short8 v = *(const short8*)(cs + rr * 64 + ((cc ^ (rr & 7)) * 8));
      *(short8*)&Cb[(size_t)(m0 + wm * 64 + rr) * ldc + n0 + wn * 64 + cc * 8] = v;
    }
  } else {
    float* cf = (float*)(void*)smem + w * 2048;
#pragma unroll
    for (int pass = 0; pass < 2; pass++) {
#pragma unroll
      for (int m2 = 0; m2 < 2; m2++)
#pragma unroll
        for (int ni = 0; ni < 4; ni++)
#pragma unroll
          for (int r = 0; r < 4; r++) {
            int row = m2 * 16 + quad * 4 + r;
            int ch  = ((ni * 4 + (l16 >> 2)) ^ (row & 15)) * 4 + (l16 & 3);
            cf[row * 64 + ch] = acc[pass * 2 + m2][ni][r] + bvv[ni];
          }
      float* Cf = (float*)C;
#pragma unroll
      for (int i = 0; i < 8; i++) {
        int ch = lane + i * 64;
        int rr = ch >> 4, cc = ch & 15;
        f32x4 v = *(const f32x4*)(cf + rr * 64 + ((cc ^ (rr & 15)) * 4));
        *(f32x4*)&Cf[(size_t)(m0 + wm * 64 + pass * 32 + rr) * ldc +
                     n0 + wn * 64 + cc * 4] = v;
      }
    }
  }
}

// ---------------------------------------------------------------------------
// V transpose: Vt[(b*16+h)*64 + d][t] = P[b*T+t][vcol(h)+d]. 64x64 LDS tiles.
// ---------------------------------------------------------------------------
__global__ __launch_bounds__(256) void vt_kernel(const u16* __restrict__ P,
                                                 u16* __restrict__ Vt)
{
  const int tt = blockIdx.x * 64;
  const int bh = blockIdx.y;
  const int b = bh >> 4, h = bh & 15;
  const int vcol = 1552 + h * HEAD_DIM;
  __shared__ u16 t[64][65];
  const int tx = threadIdx.x & 63, ty = threadIdx.x >> 6;
#pragma unroll
  for (int rr = 0; rr < 16; rr++) {
    int r = ty * 16 + rr;
    t[r][tx] = P[((size_t)b * SEQ_T + tt + r) * PNS + vcol + tx];
  }
  __syncthreads();
#pragma unroll
  for (int rr = 0; rr < 16; rr++) {
    int d = ty * 16 + rr;
    Vt[((size_t)bh * 64 + d) * SEQ_T + tt + tx] = t[tx][d];
  }
}

// ---------------------------------------------------------------------------
// Causal flash attention. ROUND 6: T12 in-register softmax via swapped 32x32
// QK^T. Rounds 1-5 showed the kernel is critical-path bound (~1000 cyc/iter,
// no pipe >26%); the largest removable path segment was the Ps LDS round-trip
// (write 32 scalars -> lgkm wait -> read). Now: QK = mfma_32x32x16(K, Q)
// [A=K rows=keys, B=Q cols=q] -> S has q IN THE LANE (col=l32) and keys in
// regs (row=(r&3)+8(r>>2)+4hi, m74/m101-verified layout). Both chains pack
// into the 32 q-cols (A=cols 0-15, B=16-31). PV A-frag (row=q=l32,
// k=8hi+e) is built IN-REGISTER per 16-key chunk: 4 cvt_pk_bf16_f32 +
// 4 shfl_xor(32) + 4 selects (keys 16c+4H+m live at H-half; the hi-half
// exchange supplies the other four). No Ps buffer at all -> LDS 48KB ->
// 3 blocks/CU (768 resident = R1's cache-safe regime). PV/rowsum are
// 32x32 mfma (P@V per d-tile; P@ones -> per-reg rowsum, same reg-q map).
// Causal mask in new layout: blanket A-col mask for kt>qtA (chain-A skip
// is gone; exp2(-inf)=0 keeps rowsum right), per-element at kt==qtA/qtB.
// R4's triple-buffer + counted vmcnt(4) staging skeleton unchanged.
// ---------------------------------------------------------------------------
__global__ __launch_bounds__(256, 3) void attn_kernel(
    const u16* __restrict__ P, const u16* __restrict__ Vt,
    u16* __restrict__ Y)
{
  const int bh  = blockIdx.x;
  const int b   = bh >> 4, h = bh & 15;
  const int p   = blockIdx.y;           // 0..15
  const int qtA = p, qtB = NTILES - 1 - p;
  const int tid = threadIdx.x;
  const int w   = tid >> 6;
  const int lane = tid & 63;
  const int l32 = lane & 31, hi = lane >> 5;
  const size_t rowb = (size_t)b * SEQ_T;
  const int qcol = 16 + h * PRIV;
  const int kcol = 784 + h * PRIV;

  __shared__ __align__(16) u16 Ks[3][64 * 64];     // [j][dchunk^(j&7)]
  __shared__ __align__(16) u16 Vs[3][64 * 64];     // [d][tchunk^(d&7)]

  const float csc = 0.18033688011112042f;  // (1/8)*log2(e)
  const int iA = qtA * 64 + w * 16, iB = qtB * 64 + w * 16;
  // per-lane q: cols 0-15 = chain A, 16-31 = chain B
  const int gi = (l32 < 16) ? (iA + l32) : (iB + l32 - 16);
  const u16* qptr = P + (rowb + gi) * PNS;

  // Q B-frag: chunk c holds d = 16c + 8hi + e (e=0..7)
  short8 qb[4];
  qb[0] = *(const short8*)&qptr[8 * hi];                       // share d 0..15
#pragma unroll
  for (int c = 1; c < 4; c++)
    qb[c] = *(const short8*)&qptr[qcol + 16 * c + 8 * hi - 16];// priv d 16..63
#pragma unroll
  for (int c = 0; c < 4; c++)
#pragma unroll
    for (int e = 0; e < 8; e++)
      qb[c][e] = (short)f2bf(bf2f((u16)qb[c][e]) * csc);

  short8 ones;
#pragma unroll
  for (int e = 0; e < 8; e++) ones[e] = (short)0x3F80;

  const int nkt = qtB + 1;   // >= 17 always

#if HAVE_GLL
#define GLOADA(g, l) gload_lds16((g), (l))
#else
#define GLOADA(g, l) (*(uint4*)(l) = *(const uint4*)(g))
#endif
#define STAGE_KV(t, bb)                                                        \
  {                                                                            \
    const int kk0 = (t) * 64;                                                  \
    _Pragma("unroll") for (int i2 = 0; i2 < 2; i2++) {                         \
      int c   = tid + i2 * 256;                                                \
      int row = c >> 3;                                                        \
      int dg  = ((c & 7) ^ (row & 7)) * 8;                                     \
      int col = (dg < 16) ? dg : (kcol + dg - 16);                             \
      GLOADA(&P[(rowb + kk0 + row) * PNS + col], &Ks[bb][c * 8]);              \
      GLOADA(&Vt[((size_t)bh * 64 + row) * SEQ_T + kk0 + dg], &Vs[bb][c * 8]); \
    }                                                                          \
  }

  f32x16 accy[2], accl;
#pragma unroll
  for (int r = 0; r < 16; r++) { accy[0][r] = 0.f; accy[1][r] = 0.f; accl[r] = 0.f; }

  const float ninf = -__builtin_inff();

  // prologue: tiles 0,1 in flight; confirm 0, leave 1 outstanding
  STAGE_KV(0, 0);
  STAGE_KV(1, 1);
  asm volatile("s_waitcnt vmcnt(4)" ::: "memory");
  __builtin_amdgcn_sched_barrier(0);
  __builtin_amdgcn_s_barrier();

  for (int kt = 0; kt < nkt; kt++) {
    const int cur = kt % 3;
    const int k0  = kt * 64;
    if (kt + 2 < nkt) STAGE_KV(kt + 2, (kt + 2) % 3);   // 2-deep prefetch

#pragma unroll
    for (int kk = 0; kk < 2; kk++) {
      // ---- S^T = K @ Q : C[key=(r&3)+8(r>>2)+4hi][q=l32] ----
      f32x16 s;
#pragma unroll
      for (int r = 0; r < 16; r++) s[r] = 0.f;
      const int krow = kk * 32 + l32;
      __builtin_amdgcn_s_setprio(1);
#pragma unroll
      for (int c = 0; c < 4; c++) {
        short8 ka = *(const short8*)&Ks[cur][krow * 64 + (((2 * c + hi) ^ (krow & 7)) * 8)];
        s = __builtin_amdgcn_mfma_f32_32x32x16_bf16(ka, qb[c], s, 0, 0, 0);
      }
      __builtin_amdgcn_s_setprio(0);

      // ---- causal mask ----
      if (kt == qtA || kt == qtB) {
#pragma unroll
        for (int r = 0; r < 16; r++) {
          int gj = k0 + kk * 32 + (r & 3) + 8 * (r >> 2) + 4 * hi;
          if (gj > gi) s[r] = ninf;
        }
      }
      if (kt > qtA) {   // chain-A cols fully masked past their diagonal
#pragma unroll
        for (int r = 0; r < 16; r++)
          if (l32 < 16) s[r] = ninf;
      }

      // ---- p = exp2(s) ----
      float px[16];
#pragma unroll
      for (int r = 0; r < 16; r++) px[r] = EXP2(s[r]);

      // ---- per 16-key chunk: in-register P->A-frag, then rowsum + PV ----
#pragma unroll
      for (int kc = 0; kc < 2; kc++) {
        unsigned g0, g1, g2, g3;
        asm("v_cvt_pk_bf16_f32 %0, %1, %2" : "=v"(g0) : "v"(px[8*kc+0]), "v"(px[8*kc+1]));
        asm("v_cvt_pk_bf16_f32 %0, %1, %2" : "=v"(g1) : "v"(px[8*kc+2]), "v"(px[8*kc+3]));
        asm("v_cvt_pk_bf16_f32 %0, %1, %2" : "=v"(g2) : "v"(px[8*kc+4]), "v"(px[8*kc+5]));
        asm("v_cvt_pk_bf16_f32 %0, %1, %2" : "=v"(g3) : "v"(px[8*kc+6]), "v"(px[8*kc+7]));
        // lane H holds keys {16kc+4H+m} in g0/g1 and {16kc+8+4H+m} in g2/g3.
        // A-frag lane hi needs keys 16kc+8hi+{0..7}: own half + partner half.
        unsigned x0 = (unsigned)__shfl_xor((int)g0, 32);
        unsigned x1 = (unsigned)__shfl_xor((int)g1, 32);
        unsigned x2 = (unsigned)__shfl_xor((int)g2, 32);
        unsigned x3 = (unsigned)__shfl_xor((int)g3, 32);
        unsigned v0 = hi ? x2 : g0;   // keys +0,+1
        unsigned v1 = hi ? x3 : g1;   // keys +2,+3
        unsigned v2 = hi ? g2 : x0;   // keys +4,+5
        unsigned v3 = hi ? g3 : x1;   // keys +6,+7
        uint32x4 pv = {v0, v1, v2, v3};
        short8 pa = __builtin_bit_cast(short8, pv);

        __builtin_amdgcn_s_setprio(1);
        accl = __builtin_amdgcn_mfma_f32_32x32x16_bf16(pa, ones, accl, 0, 0, 0);
#pragma unroll
        for (int dt = 0; dt < 2; dt++) {
          int vrow = dt * 32 + l32;
          short8 vbf = *(const short8*)&Vs[cur][vrow * 64 + (((4*kk + 2*kc + hi) ^ (vrow & 7)) * 8)];
          accy[dt] = __builtin_amdgcn_mfma_f32_32x32x16_bf16(pa, vbf, accy[dt], 0, 0, 0);
        }
        __builtin_amdgcn_s_setprio(0);
      }
    }

    // counted bottom wait: keep next-next tile's 4 loads in flight
    if (kt + 3 < nkt) {
      asm volatile("s_waitcnt vmcnt(4)" ::: "memory");
      __builtin_amdgcn_sched_barrier(0);
      __builtin_amdgcn_s_barrier();
    } else if (kt + 2 == nkt) {       // kt == nkt-2: drain the last tile
      asm volatile("s_waitcnt vmcnt(0)" ::: "memory");
      __builtin_amdgcn_sched_barrier(0);
      __builtin_amdgcn_s_barrier();
    } else if (kt + 3 == nkt) {       // kt == nkt-3: confirm tile nkt-2
      asm volatile("s_waitcnt vmcnt(4)" ::: "memory");
      __builtin_amdgcn_sched_barrier(0);
      __builtin_amdgcn_s_barrier();
    }
    // kt == nkt-1: no wait, fall through to epilogue
  }
#undef STAGE_KV
#undef GLOADA

  // ---- epilogue: C[row=q][col=d]; q=(r&3)+8(r>>2)+4hi; r<8 -> chain A ----
  float inv[16];
#pragma unroll
  for (int r = 0; r < 16; r++) inv[r] = 1.0f / accl[r];
#pragma unroll
  for (int r = 0; r < 16; r++) {
    int q = (r & 3) + 8 * (r >> 2) + 4 * hi;
    int grow = (r < 8) ? (iA + q) : (iB + q - 16);
    size_t base = (rowb + grow) * N_EMBD + h * HEAD_DIM + l32;
    Y[base]      = f2bf(accy[0][r] * inv[r]);
    Y[base + 32] = f2bf(accy[1][r] * inv[r]);
  }
}

// ---------------------------------------------------------------------------
extern "C" void kernel_launch(void* const* d_in, const int* in_sizes, int n_in,
                              void* d_out, int out_size, void* d_ws, size_t ws_size,
                              hipStream_t stream) {
  (void)in_sizes; (void)n_in; (void)out_size; (void)ws_size;
  const void* x   = d_in[0];
  const void* Wsh = d_in[1];
  const void* bsh = d_in[2];
  const void* Wq  = d_in[3];
  const void* bq  = d_in[4];
  const void* Wk  = d_in[5];
  const void* bk  = d_in[6];
  const void* Wv  = d_in[7];
  const void* bv  = d_in[8];
  const void* Wo  = d_in[9];
  const void* bo  = d_in[10];

  char* wsb = (char*)d_ws;
  int* flag = (int*)wsb;
  u16* ws16 = (u16*)(wsb + 64);
  u16* Wcat = ws16;                                   // PNS*1024 (transposed)
  u16* bcat = Wcat + (size_t)PNS * N_EMBD;            // PNS
  u16* Woc  = bcat + PNS;                             // 1024*1024 (transposed)
  u16* boc  = Woc + (size_t)N_EMBD * N_EMBD;          // 1024
  u16* Pb   = boc + N_EMBD;                           // 8192*2816
  u16* Yb   = Pb + (size_t)M_ROWS * PNS;              // 8192*1024 (also Xb)
  u16* Vtb  = Yb + (size_t)M_ROWS * N_EMBD;           // 64*64*2048
  u16* Xb   = Yb;   // x->bf16 staging aliases Yb: proj reads Xb, attn writes Yb later

  detect_kernel<<<dim3(1), dim3(256), 0, stream>>>((const u16*)x, flag);
  pack_t_kernel<<<dim3(16, 16, 6), dim3(256), 0, stream>>>(
      Wsh, Wq, Wk, Wv, Wo, bsh, bq, bk, bv, bo, Wcat, Woc, bcat, boc, flag);
  xbf_kernel<<<dim3(M_ROWS * N_EMBD / (256 * 8)), dim3(256), 0, stream>>>(
      x, Xb, flag);
  // proj GEMM: [8192 x 2816] = Xb @ Wcat^T, bf16 out
  gemm8p_kernel<<<dim3(64 * (PNS / 256)), dim3(512), 0, stream>>>(
      Xb, Wcat, bcat, Pb, PNS, 64, flag, 0);
  vt_kernel<<<dim3(SEQ_T / 64, BATCH * N_HEADS), dim3(256), 0, stream>>>(
      Pb, Vtb);
  attn_kernel<<<dim3(BATCH * N_HEADS, NTILES / 2), dim3(256), 0, stream>>>(
      Pb, Vtb, Yb);
  // out GEMM: [8192 x 1024] = Yb @ Woc^T, f32 out when inputs were f32
  gemm8p_kernel<<<dim3(64 * (N_EMBD / 256)), dim3(512), 0, stream>>>(
      Yb, Woc, boc, d_out, N_EMBD, 64, flag, 1);
}

// Round 7
// 297.147 us; speedup vs baseline: 1.0113x; 1.0113x over previous
//
#include <hip/hip_runtime.h>
#include <hip/hip_bf16.h>

typedef unsigned short u16;
typedef short short8 __attribute__((ext_vector_type(8)));
typedef float f32x4 __attribute__((ext_vector_type(4)));
typedef float f32x16 __attribute__((ext_vector_type(16)));
typedef unsigned uint32x4 __attribute__((ext_vector_type(4)));

#define N_EMBD   1024
#define N_HEADS  16
#define HEAD_DIM 64
#define PRIV     48
#define SEQ_T    2048
#define BATCH    4
#define M_ROWS   (BATCH*SEQ_T)   // 8192
#define PNS      2816            // [share 16 | q 768 | k 768 | v 1024] = 2576 -> 11*256
#define NTILES   (SEQ_T/64)      // 32
#define NT_K     16              // K=1024 / BK=64

#if __has_builtin(__builtin_amdgcn_exp2f)
#define EXP2(x) __builtin_amdgcn_exp2f(x)
#else
#define EXP2(x) exp2f(x)
#endif

#if __has_builtin(__builtin_amdgcn_global_load_lds)
#define HAVE_GLL 1
#else
#define HAVE_GLL 0
#endif

#if __has_builtin(__builtin_amdgcn_permlane32_swap)
#define HAVE_PLSWAP 1
typedef unsigned uint2v __attribute__((ext_vector_type(2)));
#else
#define HAVE_PLSWAP 0
#endif

__device__ __forceinline__ u16 f2bf(float f) {
  __hip_bfloat16 h = __float2bfloat16(f);
  return *reinterpret_cast<u16*>(&h);
}
__device__ __forceinline__ float bf2f(u16 s) {
  __hip_bfloat16 h;
  *reinterpret_cast<u16*>(&h) = s;
  return __bfloat162float(h);
}
__device__ __forceinline__ float loadv(const void* p, size_t i, int isf32) {
  return isf32 ? ((const float*)p)[i] : bf2f(((const u16*)p)[i]);
}
__device__ __forceinline__ u16 truncbf(float f) {
  unsigned u = __builtin_bit_cast(unsigned, f);
  return (u16)(u >> 16);
}
#if HAVE_GLL
__device__ __forceinline__ void gload_lds16(const u16* g, u16* l) {
  __builtin_amdgcn_global_load_lds(
      (const __attribute__((address_space(1))) void*)g,
      (__attribute__((address_space(3))) void*)l, 16, 0, 0);
}
#endif

// ---------------------------------------------------------------------------
// Dtype detector (1 = f32 inputs).
// ---------------------------------------------------------------------------
__global__ __launch_bounds__(256) void detect_kernel(const u16* __restrict__ x,
                                                     int* __restrict__ flag) {
  __shared__ int cnt;
  if (threadIdx.x == 0) cnt = 0;
  __syncthreads();
  u16 v = x[2 * threadIdx.x];
  int e = (v >> 7) & 0xFF;
  int junk = (e >= 0xC0 || (e != 0 && e <= 0x30)) ? 1 : 0;
  if (junk) atomicAdd(&cnt, 1);
  __syncthreads();
  if (threadIdx.x == 0) *flag = (cnt > 16) ? 1 : 0;
}

// ---------------------------------------------------------------------------
// Transposing pack (weights -> [n][k] bf16) + z=5 slice does zero-pad + biases.
// ---------------------------------------------------------------------------
__global__ __launch_bounds__(256) void pack_t_kernel(
    const void* __restrict__ Wsh, const void* __restrict__ Wq,
    const void* __restrict__ Wk,  const void* __restrict__ Wv,
    const void* __restrict__ Wo,
    const void* __restrict__ bsh, const void* __restrict__ bq,
    const void* __restrict__ bk,  const void* __restrict__ bv,
    const void* __restrict__ bo,
    u16* __restrict__ Wcat, u16* __restrict__ Woc,
    u16* __restrict__ bcat, u16* __restrict__ boc,
    const int* __restrict__ flagp)
{
  const int f = *flagp;
  if (blockIdx.z == 5) {  // pad + biases
    const int flat = blockIdx.y * 16 + blockIdx.x;
    const int padN = (PNS - 2576) * 1024;
    for (int i = flat * 256 + threadIdx.x; i < padN; i += 256 * 256)
      Wcat[(size_t)2576 * 1024 + i] = 0;
    if (flat == 0) {
      for (int c = threadIdx.x; c < PNS; c += 256) {
        float v = 0.f;
        if (c < 16)        v = loadv(bsh, c, f);
        else if (c < 784)  v = loadv(bq, c - 16, f);
        else if (c < 1552) v = loadv(bk, c - 784, f);
        else if (c < 2576) v = loadv(bv, c - 1552, f);
        bcat[c] = f2bf(v);
      }
    } else if (flat == 1) {
      for (int c = threadIdx.x; c < N_EMBD; c += 256)
        boc[c] = f2bf(loadv(bo, c, f));
    }
    return;
  }
  const void* src; u16* dst; int N, rowOff;
  switch (blockIdx.z) {
    case 0: src = Wsh; dst = Wcat; N = 16;   rowOff = 0;    break;
    case 1: src = Wq;  dst = Wcat; N = 768;  rowOff = 16;   break;
    case 2: src = Wk;  dst = Wcat; N = 768;  rowOff = 784;  break;
    case 3: src = Wv;  dst = Wcat; N = 1024; rowOff = 1552; break;
    default:src = Wo;  dst = Woc;  N = 1024; rowOff = 0;    break;
  }
  const int n0 = blockIdx.x * 64;
  if (n0 >= N) return;
  const int k0 = blockIdx.y * 64;
  __shared__ u16 t[64][65];
  const int tx = threadIdx.x & 63, ty = threadIdx.x >> 6;
#pragma unroll
  for (int rr = 0; rr < 16; rr++) {
    int k = k0 + ty * 16 + rr;
    int n = n0 + tx;
    float v = (n < N) ? loadv(src, (size_t)k * N + n, f) : 0.f;
    t[ty * 16 + rr][tx] = f2bf(v);
  }
  __syncthreads();
#pragma unroll
  for (int rr = 0; rr < 16; rr++) {
    int n = ty * 16 + rr;
    if (n0 + n < N)
      dst[(size_t)(rowOff + n0 + n) * 1024 + k0 + tx] = t[tx][n];
  }
}

// ---------------------------------------------------------------------------
// x (f32 or bf16 per flag) -> Xb bf16 [8192][1024]. 8 elems/thread.
// ---------------------------------------------------------------------------
__global__ __launch_bounds__(256) void xbf_kernel(const void* __restrict__ x,
                                                  u16* __restrict__ Xb,
                                                  const int* __restrict__ flagp) {
  const int f = *flagp;
  const size_t i = (size_t)blockIdx.x * 256 + threadIdx.x;
  if (f) {
    const float4* p = (const float4*)x;
    float4 a = p[i * 2], b = p[i * 2 + 1];
    u16 t[8] = {f2bf(a.x), f2bf(a.y), f2bf(a.z), f2bf(a.w),
                f2bf(b.x), f2bf(b.y), f2bf(b.z), f2bf(b.w)};
    *(uint4*)&Xb[i * 8] = *(const uint4*)t;
  } else {
    *(uint4*)&Xb[i * 8] = ((const uint4*)x)[i];
  }
}

// ---------------------------------------------------------------------------
// 8-wave deep-pipelined bf16 GEMM: C(MxN) = A(MxK=1024) @ Bt(NxK)^T + bias.
// Tile BM=128 x BN=256, BK=64. 512 thr = 8 waves (2M x 4N), 64x64 out/wave.
// Triple-buffered LDS; counted vmcnt(6) schedule (T3+T4); T2 XOR swizzle;
// T5 setprio. Unchanged since round 1.
// ---------------------------------------------------------------------------
__global__ __launch_bounds__(512, 2) void gemm8p_kernel(
    const u16* __restrict__ A,    // [M][1024] bf16
    const u16* __restrict__ Bt,   // [N][1024] bf16
    const u16* __restrict__ bias, // [N] bf16
    void* __restrict__ C, int ldc, int Mtiles,
    const int* __restrict__ flagp, int c_dyn)
{
  __shared__ __align__(16) u16 smem[73728];   // 147456 B
  u16* const As = smem;                       // 3 x [128*64]
  u16* const Bs = smem + 3 * 8192;            // 3 x [256*64]

  const bool cf32 = (c_dyn != 0) && (*flagp != 0);

  const int tid  = threadIdx.x;
  const int lane = tid & 63;
  const int w    = tid >> 6;
  const int quad = lane >> 4, l16 = lane & 15;
  const int wm   = w >> 2, wn = w & 3;

  const int nwg = gridDim.x;
  const int wg  = (blockIdx.x & 7) * (nwg >> 3) + (blockIdx.x >> 3);
  const int mb  = wg % Mtiles, nb = wg / Mtiles;
  const int m0  = mb * 128, n0 = nb * 256;

  int ldsA[2]; size_t glA[2];
  int ldsB[2][2]; size_t glB[2][2];
#pragma unroll
  for (int rd = 0; rd < 2; rd++) {
    int j = tid + rd * 512, rp = j >> 3, s = j & 7;
    int cl = (s ^ (rp & 7)) * 8;
    ldsA[rd] = rp * 64 + s * 8;
    glA[rd]  = (size_t)(m0 + rp) * 1024 + cl;
#pragma unroll
    for (int nh = 0; nh < 2; nh++) {
      int cc = (rp & 31) + nh * 32 + (rp >> 5) * 64;
      ldsB[nh][rd] = cc * 64 + s * 8;
      glB[nh][rd]  = (size_t)(n0 + cc) * 1024 + cl;
    }
  }

#if HAVE_GLL
#define G8(g, l) gload_lds16((g), (l))
#else
#define G8(g, l) (*(uint4*)(l) = *(const uint4*)(g))
#endif
#define STG_A(t, bf)                                                       \
  if ((t) < NT_K) {                                                        \
    _Pragma("unroll") for (int rd = 0; rd < 2; rd++)                       \
      G8(A + glA[rd] + (t) * 64, As + (bf) * 8192 + ldsA[rd]);             \
  }
#define STG_B(nh, t, bf)                                                   \
  if ((t) < NT_K) {                                                        \
    _Pragma("unroll") for (int rd = 0; rd < 2; rd++)                       \
      G8(Bt + glB[nh][rd] + (t) * 64, Bs + (bf) * 16384 + ldsB[nh][rd]);   \
  }

  const int ck0  = ((quad)     ^ (l16 & 7)) * 8;
  const int ck1  = ((4 + quad) ^ (l16 & 7)) * 8;
  const int arow = (wm * 64 + l16) * 64;
  const int brow = (wn * 64 + l16) * 64;

  f32x4 acc[4][4];
#pragma unroll
  for (int i = 0; i < 4; i++)
#pragma unroll
    for (int j = 0; j < 4; j++) acc[i][j] = (f32x4){0.f, 0.f, 0.f, 0.f};

  short8 af[4][2], bA[2][2], bB[2][2];

#define READ_A(cur)                                                        \
  { const u16* pa = As + (cur) * 8192 + arow;                              \
    _Pragma("unroll") for (int m = 0; m < 4; m++) {                        \
      af[m][0] = *(const short8*)(pa + m * 1024 + ck0);                    \
      af[m][1] = *(const short8*)(pa + m * 1024 + ck1); } }
#define READ_B(dst, nh, cur)                                               \
  { const u16* pb = Bs + (cur) * 16384 + brow + (nh) * 2048;               \
    _Pragma("unroll") for (int n = 0; n < 2; n++) {                        \
      dst[n][0] = *(const short8*)(pb + n * 1024 + ck0);                   \
      dst[n][1] = *(const short8*)(pb + n * 1024 + ck1); } }
#define MM16(bfr, nh)                                                      \
  __builtin_amdgcn_s_setprio(1);                                           \
  _Pragma("unroll") for (int m = 0; m < 4; m++)                            \
    _Pragma("unroll") for (int n = 0; n < 2; n++) {                        \
      acc[m][(nh)*2+n] = __builtin_amdgcn_mfma_f32_16x16x32_bf16(          \
          af[m][0], bfr[n][0], acc[m][(nh)*2+n], 0, 0, 0);                 \
      acc[m][(nh)*2+n] = __builtin_amdgcn_mfma_f32_16x16x32_bf16(          \
          af[m][1], bfr[n][1], acc[m][(nh)*2+n], 0, 0, 0); }               \
  __builtin_amdgcn_s_setprio(0);
#define BARR { __builtin_amdgcn_s_barrier(); __builtin_amdgcn_sched_barrier(0); }

  STG_A(0, 0); STG_B(1, 0, 0); STG_B(0, 0, 0);
  STG_A(1, 1); STG_B(1, 1, 1); STG_B(0, 1, 1);
  asm volatile("s_waitcnt vmcnt(6)");
  BARR;

#pragma unroll
  for (int kt = 0; kt < NT_K; kt++) {
    const int cur = kt % 3;
    const int stb = (kt + 2) % 3;
    READ_A(cur); READ_B(bA, 0, cur);
    STG_A(kt + 2, stb); STG_B(1, kt + 2, stb);
    BARR;
    MM16(bA, 0);
    BARR;
    READ_B(bB, 1, cur);
    STG_B(0, kt + 2, stb);
    BARR;
    MM16(bB, 1);
    if (kt < NT_K - 2)       { asm volatile("s_waitcnt vmcnt(6)"); }
    else if (kt == NT_K - 2) { asm volatile("s_waitcnt vmcnt(0)"); }
    BARR;
  }
#undef STG_A
#undef STG_B
#undef READ_A
#undef READ_B
#undef MM16
#undef BARR
#undef G8

  float bvv[4];
#pragma unroll
  for (int ni = 0; ni < 4; ni++)
    bvv[ni] = bf2f(bias[n0 + wn * 64 + ni * 16 + l16]);

  if (!cf32) {
    u16* cs = smem + w * 4096;
#pragma unroll
    for (int m = 0; m < 4; m++)
#pragma unroll
      for (int ni = 0; ni < 4; ni++)
#pragma unroll
        for (int r = 0; r < 4; r++) {
          int row = m * 16 + quad * 4 + r;
          int ch  = ((ni * 2 + (l16 >> 3)) ^ (row & 7)) * 8 + (l16 & 7);
          cs[row * 64 + ch] = f2bf(acc[m][ni][r] + bvv[ni]);
        }
    u16* Cb = (u16*)C;
#pragma unroll
    for (int i = 0; i < 8; i++) {
      int ch = lane + i * 64;
      int rr = ch >> 3, cc = ch & 7;
      short8 v = *(const short8*)(cs + rr * 64 + ((cc ^ (rr & 7)) * 8));
      *(short8*)&Cb[(size_t)(m0 + wm * 64 + rr) * ldc + n0 + wn * 64 + cc * 8] = v;
    }
  } else {
    float* cf = (float*)(void*)smem + w * 2048;
#pragma unroll
    for (int pass = 0; pass < 2; pass++) {
#pragma unroll
      for (int m2 = 0; m2 < 2; m2++)
#pragma unroll
        for (int ni = 0; ni < 4; ni++)
#pragma unroll
          for (int r = 0; r < 4; r++) {
            int row = m2 * 16 + quad * 4 + r;
            int ch  = ((ni * 4 + (l16 >> 2)) ^ (row & 15)) * 4 + (l16 & 3);
            cf[row * 64 + ch] = acc[pass * 2 + m2][ni][r] + bvv[ni];
          }
      float* Cf = (float*)C;
#pragma unroll
      for (int i = 0; i < 8; i++) {
        int ch = lane + i * 64;
        int rr = ch >> 4, cc = ch & 15;
        f32x4 v = *(const f32x4*)(cf + rr * 64 + ((cc ^ (rr & 15)) * 4));
        *(f32x4*)&Cf[(size_t)(m0 + wm * 64 + pass * 32 + rr) * ldc +
                     n0 + wn * 64 + cc * 4] = v;
      }
    }
  }
}

// ---------------------------------------------------------------------------
// V transpose: Vt[(b*16+h)*64 + d][t] = P[b*T+t][vcol(h)+d]. 64x64 LDS tiles.
// ---------------------------------------------------------------------------
__global__ __launch_bounds__(256) void vt_kernel(const u16* __restrict__ P,
                                                 u16* __restrict__ Vt)
{
  const int tt = blockIdx.x * 64;
  const int bh = blockIdx.y;
  const int b = bh >> 4, h = bh & 15;
  const int vcol = 1552 + h * HEAD_DIM;
  __shared__ u16 t[64][65];
  const int tx = threadIdx.x & 63, ty = threadIdx.x >> 6;
#pragma unroll
  for (int rr = 0; rr < 16; rr++) {
    int r = ty * 16 + rr;
    t[r][tx] = P[((size_t)b * SEQ_T + tt + r) * PNS + vcol + tx];
  }
  __syncthreads();
#pragma unroll
  for (int rr = 0; rr < 16; rr++) {
    int d = ty * 16 + rr;
    Vt[((size_t)bh * 64 + d) * SEQ_T + tt + tx] = t[tx][d];
  }
}

// ---------------------------------------------------------------------------
// Causal flash attention, swapped 32x32 QK^T + in-register softmax (T12).
// ROUND 7: round-6's regression was fully explained by SQ_LDS_BANK_CONFLICT
// 0 -> 6.42M = EXACTLY 8.0 conflict-cycles per __shfl_xor(..,32): xor-32
// crosses the 32-lane boundary, so hipcc emits ds_bpermute_b32 (16/iter on
// the serial exp2->PV path). Fix: v_permlane32_swap_b32 (the real T12
// primitive). Semantics: new_a = [a.lo | b.lo(partner)], new_b =
// [a.hi(partner) | b.hi] -- so ONE swap of (g0,g2) yields BOTH A-frag words
// v0=r.x, v2=r.y (verified element-wise vs the round-6 select logic), and
// (g1,g3) yields v1,v3. Per 16-key chunk: 4 cvt_pk + 2 permlane replaces
// 4 cvt_pk + 4 bpermute + 4 cndmask. Zero LDS-path ops in the softmax
// hand-off. Everything else unchanged from round 6 (isolating the fix):
// LDS 48KB -> 3 blocks/CU; triple-buffer + counted vmcnt(4); 32x32 MFMAs;
// blanket A-mask for kt>qtA; per-element mask at diagonal tiles.
// ---------------------------------------------------------------------------
__global__ __launch_bounds__(256, 3) void attn_kernel(
    const u16* __restrict__ P, const u16* __restrict__ Vt,
    u16* __restrict__ Y)
{
  const int bh  = blockIdx.x;
  const int b   = bh >> 4, h = bh & 15;
  const int p   = blockIdx.y;           // 0..15
  const int qtA = p, qtB = NTILES - 1 - p;
  const int tid = threadIdx.x;
  const int w   = tid >> 6;
  const int lane = tid & 63;
  const int l32 = lane & 31, hi = lane >> 5;
  const size_t rowb = (size_t)b * SEQ_T;
  const int qcol = 16 + h * PRIV;
  const int kcol = 784 + h * PRIV;

  __shared__ __align__(16) u16 Ks[3][64 * 64];     // [j][dchunk^(j&7)]
  __shared__ __align__(16) u16 Vs[3][64 * 64];     // [d][tchunk^(d&7)]

  const float csc = 0.18033688011112042f;  // (1/8)*log2(e)
  const int iA = qtA * 64 + w * 16, iB = qtB * 64 + w * 16;
  // per-lane q: cols 0-15 = chain A, 16-31 = chain B
  const int gi = (l32 < 16) ? (iA + l32) : (iB + l32 - 16);
  const u16* qptr = P + (rowb + gi) * PNS;

  // Q B-frag: chunk c holds d = 16c + 8hi + e (e=0..7)
  short8 qb[4];
  qb[0] = *(const short8*)&qptr[8 * hi];                       // share d 0..15
#pragma unroll
  for (int c = 1; c < 4; c++)
    qb[c] = *(const short8*)&qptr[qcol + 16 * c + 8 * hi - 16];// priv d 16..63
#pragma unroll
  for (int c = 0; c < 4; c++)
#pragma unroll
    for (int e = 0; e < 8; e++)
      qb[c][e] = (short)f2bf(bf2f((u16)qb[c][e]) * csc);

  short8 ones;
#pragma unroll
  for (int e = 0; e < 8; e++) ones[e] = (short)0x3F80;

  const int nkt = qtB + 1;   // >= 17 always

#if HAVE_GLL
#define GLOADA(g, l) gload_lds16((g), (l))
#else
#define GLOADA(g, l) (*(uint4*)(l) = *(const uint4*)(g))
#endif
#define STAGE_KV(t, bb)                                                        \
  {                                                                            \
    const int kk0 = (t) * 64;                                                  \
    _Pragma("unroll") for (int i2 = 0; i2 < 2; i2++) {                         \
      int c   = tid + i2 * 256;                                                \
      int row = c >> 3;                                                        \
      int dg  = ((c & 7) ^ (row & 7)) * 8;                                     \
      int col = (dg < 16) ? dg : (kcol + dg - 16);                             \
      GLOADA(&P[(rowb + kk0 + row) * PNS + col], &Ks[bb][c * 8]);              \
      GLOADA(&Vt[((size_t)bh * 64 + row) * SEQ_T + kk0 + dg], &Vs[bb][c * 8]); \
    }                                                                          \
  }

  f32x16 accy[2], accl;
#pragma unroll
  for (int r = 0; r < 16; r++) { accy[0][r] = 0.f; accy[1][r] = 0.f; accl[r] = 0.f; }

  const float ninf = -__builtin_inff();

  // prologue: tiles 0,1 in flight; confirm 0, leave 1 outstanding
  STAGE_KV(0, 0);
  STAGE_KV(1, 1);
  asm volatile("s_waitcnt vmcnt(4)" ::: "memory");
  __builtin_amdgcn_sched_barrier(0);
  __builtin_amdgcn_s_barrier();

  for (int kt = 0; kt < nkt; kt++) {
    const int cur = kt % 3;
    const int k0  = kt * 64;
    if (kt + 2 < nkt) STAGE_KV(kt + 2, (kt + 2) % 3);   // 2-deep prefetch

#pragma unroll
    for (int kk = 0; kk < 2; kk++) {
      // ---- S^T = K @ Q : C[key=(r&3)+8(r>>2)+4hi][q=l32] ----
      f32x16 s;
#pragma unroll
      for (int r = 0; r < 16; r++) s[r] = 0.f;
      const int krow = kk * 32 + l32;
      __builtin_amdgcn_s_setprio(1);
#pragma unroll
      for (int c = 0; c < 4; c++) {
        short8 ka = *(const short8*)&Ks[cur][krow * 64 + (((2 * c + hi) ^ (krow & 7)) * 8)];
        s = __builtin_amdgcn_mfma_f32_32x32x16_bf16(ka, qb[c], s, 0, 0, 0);
      }
      __builtin_amdgcn_s_setprio(0);

      // ---- causal mask ----
      if (kt == qtA || kt == qtB) {
#pragma unroll
        for (int r = 0; r < 16; r++) {
          int gj = k0 + kk * 32 + (r & 3) + 8 * (r >> 2) + 4 * hi;
          if (gj > gi) s[r] = ninf;
        }
      }
      if (kt > qtA) {   // chain-A cols fully masked past their diagonal
#pragma unroll
        for (int r = 0; r < 16; r++)
          if (l32 < 16) s[r] = ninf;
      }

      // ---- p = exp2(s) ----
      float px[16];
#pragma unroll
      for (int r = 0; r < 16; r++) px[r] = EXP2(s[r]);

      // ---- per 16-key chunk: in-register P->A-frag, then rowsum + PV ----
#pragma unroll
      for (int kc = 0; kc < 2; kc++) {
        unsigned g0, g1, g2, g3;
        asm("v_cvt_pk_bf16_f32 %0, %1, %2" : "=v"(g0) : "v"(px[8*kc+0]), "v"(px[8*kc+1]));
        asm("v_cvt_pk_bf16_f32 %0, %1, %2" : "=v"(g1) : "v"(px[8*kc+2]), "v"(px[8*kc+3]));
        asm("v_cvt_pk_bf16_f32 %0, %1, %2" : "=v"(g2) : "v"(px[8*kc+4]), "v"(px[8*kc+5]));
        asm("v_cvt_pk_bf16_f32 %0, %1, %2" : "=v"(g3) : "v"(px[8*kc+6]), "v"(px[8*kc+7]));
        // lane H holds keys {16kc+4H+m} in g0/g1 and {16kc+8+4H+m} in g2/g3.
        // A-frag lane hi needs keys 16kc+8hi+{0..7}: own half + partner half.
#if HAVE_PLSWAP
        // permlane32_swap(a,b): new_a=[a.lo|b.lo(partner)], new_b=[a.hi(partner)|b.hi]
        uint2v r02 = __builtin_amdgcn_permlane32_swap(g0, g2, false, false);
        uint2v r13 = __builtin_amdgcn_permlane32_swap(g1, g3, false, false);
        uint32x4 pv = {r02.x, r13.x, r02.y, r13.y};
#else
        unsigned x0 = (unsigned)__shfl_xor((int)g0, 32);
        unsigned x1 = (unsigned)__shfl_xor((int)g1, 32);
        unsigned x2 = (unsigned)__shfl_xor((int)g2, 32);
        unsigned x3 = (unsigned)__shfl_xor((int)g3, 32);
        unsigned v0 = hi ? x2 : g0;
        unsigned v1 = hi ? x3 : g1;
        unsigned v2 = hi ? g2 : x0;
        unsigned v3 = hi ? g3 : x1;
        uint32x4 pv = {v0, v1, v2, v3};
#endif
        short8 pa = __builtin_bit_cast(short8, pv);

        __builtin_amdgcn_s_setprio(1);
        accl = __builtin_amdgcn_mfma_f32_32x32x16_bf16(pa, ones, accl, 0, 0, 0);
#pragma unroll
        for (int dt = 0; dt < 2; dt++) {
          int vrow = dt * 32 + l32;
          short8 vbf = *(const short8*)&Vs[cur][vrow * 64 + (((4*kk + 2*kc + hi) ^ (vrow & 7)) * 8)];
          accy[dt] = __builtin_amdgcn_mfma_f32_32x32x16_bf16(pa, vbf, accy[dt], 0, 0, 0);
        }
        __builtin_amdgcn_s_setprio(0);
      }
    }

    // counted bottom wait: keep next-next tile's 4 loads in flight
    if (kt + 3 < nkt) {
      asm volatile("s_waitcnt vmcnt(4)" ::: "memory");
      __builtin_amdgcn_sched_barrier(0);
      __builtin_amdgcn_s_barrier();
    } else if (kt + 2 == nkt) {       // kt == nkt-2: drain the last tile
      asm volatile("s_waitcnt vmcnt(0)" ::: "memory");
      __builtin_amdgcn_sched_barrier(0);
      __builtin_amdgcn_s_barrier();
    } else if (kt + 3 == nkt) {       // kt == nkt-3: confirm tile nkt-2
      asm volatile("s_waitcnt vmcnt(4)" ::: "memory");
      __builtin_amdgcn_sched_barrier(0);
      __builtin_amdgcn_s_barrier();
    }
    // kt == nkt-1: no wait, fall through to epilogue
  }
#undef STAGE_KV
#undef GLOADA

  // ---- epilogue: C[row=q][col=d]; q=(r&3)+8(r>>2)+4hi; r<8 -> chain A ----
  float inv[16];
#pragma unroll
  for (int r = 0; r < 16; r++) inv[r] = 1.0f / accl[r];
#pragma unroll
  for (int r = 0; r < 16; r++) {
    int q = (r & 3) + 8 * (r >> 2) + 4 * hi;
    int grow = (r < 8) ? (iA + q) : (iB + q - 16);
    size_t base = (rowb + grow) * N_EMBD + h * HEAD_DIM + l32;
    Y[base]      = f2bf(accy[0][r] * inv[r]);
    Y[base + 32] = f2bf(accy[1][r] * inv[r]);
  }
}

// ---------------------------------------------------------------------------
extern "C" void kernel_launch(void* const* d_in, const int* in_sizes, int n_in,
                              void* d_out, int out_size, void* d_ws, size_t ws_size,
                              hipStream_t stream) {
  (void)in_sizes; (void)n_in; (void)out_size; (void)ws_size;
  const void* x   = d_in[0];
  const void* Wsh = d_in[1];
  const void* bsh = d_in[2];
  const void* Wq  = d_in[3];
  const void* bq  = d_in[4];
  const void* Wk  = d_in[5];
  const void* bk  = d_in[6];
  const void* Wv  = d_in[7];
  const void* bv  = d_in[8];
  const void* Wo  = d_in[9];
  const void* bo  = d_in[10];

  char* wsb = (char*)d_ws;
  int* flag = (int*)wsb;
  u16* ws16 = (u16*)(wsb + 64);
  u16* Wcat = ws16;                                   // PNS*1024 (transposed)
  u16* bcat = Wcat + (size_t)PNS * N_EMBD;            // PNS
  u16* Woc  = bcat + PNS;                             // 1024*1024 (transposed)
  u16* boc  = Woc + (size_t)N_EMBD * N_EMBD;          // 1024
  u16* Pb   = boc + N_EMBD;                           // 8192*2816
  u16* Yb   = Pb + (size_t)M_ROWS * PNS;              // 8192*1024 (also Xb)
  u16* Vtb  = Yb + (size_t)M_ROWS * N_EMBD;           // 64*64*2048
  u16* Xb   = Yb;   // x->bf16 staging aliases Yb: proj reads Xb, attn writes Yb later

  detect_kernel<<<dim3(1), dim3(256), 0, stream>>>((const u16*)x, flag);
  pack_t_kernel<<<dim3(16, 16, 6), dim3(256), 0, stream>>>(
      Wsh, Wq, Wk, Wv, Wo, bsh, bq, bk, bv, bo, Wcat, Woc, bcat, boc, flag);
  xbf_kernel<<<dim3(M_ROWS * N_EMBD / (256 * 8)), dim3(256), 0, stream>>>(
      x, Xb, flag);
  // proj GEMM: [8192 x 2816] = Xb @ Wcat^T, bf16 out
  gemm8p_kernel<<<dim3(64 * (PNS / 256)), dim3(512), 0, stream>>>(
      Xb, Wcat, bcat, Pb, PNS, 64, flag, 0);
  vt_kernel<<<dim3(SEQ_T / 64, BATCH * N_HEADS), dim3(256), 0, stream>>>(
      Pb, Vtb);
  attn_kernel<<<dim3(BATCH * N_HEADS, NTILES / 2), dim3(256), 0, stream>>>(
      Pb, Vtb, Yb);
  // out GEMM: [8192 x 1024] = Yb @ Woc^T, f32 out when inputs were f32
  gemm8p_kernel<<<dim3(64 * (N_EMBD / 256)), dim3(512), 0, stream>>>(
      Yb, Woc, boc, d_out, N_EMBD, 64, flag, 1);
}

// Round 8
// 275.250 us; speedup vs baseline: 1.0918x; 1.0796x over previous
//
#include <hip/hip_runtime.h>
#include <hip/hip_bf16.h>

typedef unsigned short u16;
typedef short short8 __attribute__((ext_vector_type(8)));
typedef float f32x4 __attribute__((ext_vector_type(4)));
typedef float f32x16 __attribute__((ext_vector_type(16)));
typedef unsigned uint32x4 __attribute__((ext_vector_type(4)));

#define N_EMBD   1024
#define N_HEADS  16
#define HEAD_DIM 64
#define PRIV     48
#define SEQ_T    2048
#define BATCH    4
#define M_ROWS   (BATCH*SEQ_T)   // 8192
#define PNS      2816            // [share 16 | q 768 | k 768 | v 1024] = 2576 -> 11*256
#define NTILES   (SEQ_T/64)      // 32
#define NT_K     16              // K=1024 / BK=64

#if __has_builtin(__builtin_amdgcn_exp2f)
#define EXP2(x) __builtin_amdgcn_exp2f(x)
#else
#define EXP2(x) exp2f(x)
#endif

#if __has_builtin(__builtin_amdgcn_global_load_lds)
#define HAVE_GLL 1
#else
#define HAVE_GLL 0
#endif

#if __has_builtin(__builtin_amdgcn_permlane32_swap)
#define HAVE_PLSWAP 1
typedef unsigned uint2v __attribute__((ext_vector_type(2)));
#else
#define HAVE_PLSWAP 0
#endif

__device__ __forceinline__ u16 f2bf(float f) {
  __hip_bfloat16 h = __float2bfloat16(f);
  return *reinterpret_cast<u16*>(&h);
}
__device__ __forceinline__ float bf2f(u16 s) {
  __hip_bfloat16 h;
  *reinterpret_cast<u16*>(&h) = s;
  return __bfloat162float(h);
}
__device__ __forceinline__ float loadv(const void* p, size_t i, int isf32) {
  return isf32 ? ((const float*)p)[i] : bf2f(((const u16*)p)[i]);
}
__device__ __forceinline__ u16 truncbf(float f) {
  unsigned u = __builtin_bit_cast(unsigned, f);
  return (u16)(u >> 16);
}
#if HAVE_GLL
__device__ __forceinline__ void gload_lds16(const u16* g, u16* l) {
  __builtin_amdgcn_global_load_lds(
      (const __attribute__((address_space(1))) void*)g,
      (__attribute__((address_space(3))) void*)l, 16, 0, 0);
}
#endif

// ---------------------------------------------------------------------------
// Dtype detector (1 = f32 inputs).
// ---------------------------------------------------------------------------
__global__ __launch_bounds__(256) void detect_kernel(const u16* __restrict__ x,
                                                     int* __restrict__ flag) {
  __shared__ int cnt;
  if (threadIdx.x == 0) cnt = 0;
  __syncthreads();
  u16 v = x[2 * threadIdx.x];
  int e = (v >> 7) & 0xFF;
  int junk = (e >= 0xC0 || (e != 0 && e <= 0x30)) ? 1 : 0;
  if (junk) atomicAdd(&cnt, 1);
  __syncthreads();
  if (threadIdx.x == 0) *flag = (cnt > 16) ? 1 : 0;
}

// ---------------------------------------------------------------------------
// Transposing pack (weights -> [n][k] bf16) + z=5 slice does zero-pad + biases.
// ---------------------------------------------------------------------------
__global__ __launch_bounds__(256) void pack_t_kernel(
    const void* __restrict__ Wsh, const void* __restrict__ Wq,
    const void* __restrict__ Wk,  const void* __restrict__ Wv,
    const void* __restrict__ Wo,
    const void* __restrict__ bsh, const void* __restrict__ bq,
    const void* __restrict__ bk,  const void* __restrict__ bv,
    const void* __restrict__ bo,
    u16* __restrict__ Wcat, u16* __restrict__ Woc,
    u16* __restrict__ bcat, u16* __restrict__ boc,
    const int* __restrict__ flagp)
{
  const int f = *flagp;
  if (blockIdx.z == 5) {  // pad + biases
    const int flat = blockIdx.y * 16 + blockIdx.x;
    const int padN = (PNS - 2576) * 1024;
    for (int i = flat * 256 + threadIdx.x; i < padN; i += 256 * 256)
      Wcat[(size_t)2576 * 1024 + i] = 0;
    if (flat == 0) {
      for (int c = threadIdx.x; c < PNS; c += 256) {
        float v = 0.f;
        if (c < 16)        v = loadv(bsh, c, f);
        else if (c < 784)  v = loadv(bq, c - 16, f);
        else if (c < 1552) v = loadv(bk, c - 784, f);
        else if (c < 2576) v = loadv(bv, c - 1552, f);
        bcat[c] = f2bf(v);
      }
    } else if (flat == 1) {
      for (int c = threadIdx.x; c < N_EMBD; c += 256)
        boc[c] = f2bf(loadv(bo, c, f));
    }
    return;
  }
  const void* src; u16* dst; int N, rowOff;
  switch (blockIdx.z) {
    case 0: src = Wsh; dst = Wcat; N = 16;   rowOff = 0;    break;
    case 1: src = Wq;  dst = Wcat; N = 768;  rowOff = 16;   break;
    case 2: src = Wk;  dst = Wcat; N = 768;  rowOff = 784;  break;
    case 3: src = Wv;  dst = Wcat; N = 1024; rowOff = 1552; break;
    default:src = Wo;  dst = Woc;  N = 1024; rowOff = 0;    break;
  }
  const int n0 = blockIdx.x * 64;
  if (n0 >= N) return;
  const int k0 = blockIdx.y * 64;
  __shared__ u16 t[64][65];
  const int tx = threadIdx.x & 63, ty = threadIdx.x >> 6;
#pragma unroll
  for (int rr = 0; rr < 16; rr++) {
    int k = k0 + ty * 16 + rr;
    int n = n0 + tx;
    float v = (n < N) ? loadv(src, (size_t)k * N + n, f) : 0.f;
    t[ty * 16 + rr][tx] = f2bf(v);
  }
  __syncthreads();
#pragma unroll
  for (int rr = 0; rr < 16; rr++) {
    int n = ty * 16 + rr;
    if (n0 + n < N)
      dst[(size_t)(rowOff + n0 + n) * 1024 + k0 + tx] = t[tx][n];
  }
}

// ---------------------------------------------------------------------------
// x (f32 or bf16 per flag) -> Xb bf16 [8192][1024]. 8 elems/thread.
// ---------------------------------------------------------------------------
__global__ __launch_bounds__(256) void xbf_kernel(const void* __restrict__ x,
                                                  u16* __restrict__ Xb,
                                                  const int* __restrict__ flagp) {
  const int f = *flagp;
  const size_t i = (size_t)blockIdx.x * 256 + threadIdx.x;
  if (f) {
    const float4* p = (const float4*)x;
    float4 a = p[i * 2], b = p[i * 2 + 1];
    u16 t[8] = {f2bf(a.x), f2bf(a.y), f2bf(a.z), f2bf(a.w),
                f2bf(b.x), f2bf(b.y), f2bf(b.z), f2bf(b.w)};
    *(uint4*)&Xb[i * 8] = *(const uint4*)t;
  } else {
    *(uint4*)&Xb[i * 8] = ((const uint4*)x)[i];
  }
}

// ---------------------------------------------------------------------------
// 8-wave deep-pipelined bf16 GEMM: C(MxN) = A(MxK=1024) @ Bt(NxK)^T + bias.
// Tile BM=128 x BN=256, BK=64. 512 thr = 8 waves (2M x 4N), 64x64 out/wave.
// Triple-buffered LDS; counted vmcnt(6) schedule (T3+T4); T2 XOR swizzle;
// T5 setprio. Unchanged since round 1.
// ---------------------------------------------------------------------------
__global__ __launch_bounds__(512, 2) void gemm8p_kernel(
    const u16* __restrict__ A,    // [M][1024] bf16
    const u16* __restrict__ Bt,   // [N][1024] bf16
    const u16* __restrict__ bias, // [N] bf16
    void* __restrict__ C, int ldc, int Mtiles,
    const int* __restrict__ flagp, int c_dyn)
{
  __shared__ __align__(16) u16 smem[73728];   // 147456 B
  u16* const As = smem;                       // 3 x [128*64]
  u16* const Bs = smem + 3 * 8192;            // 3 x [256*64]

  const bool cf32 = (c_dyn != 0) && (*flagp != 0);

  const int tid  = threadIdx.x;
  const int lane = tid & 63;
  const int w    = tid >> 6;
  const int quad = lane >> 4, l16 = lane & 15;
  const int wm   = w >> 2, wn = w & 3;

  const int nwg = gridDim.x;
  const int wg  = (blockIdx.x & 7) * (nwg >> 3) + (blockIdx.x >> 3);
  const int mb  = wg % Mtiles, nb = wg / Mtiles;
  const int m0  = mb * 128, n0 = nb * 256;

  int ldsA[2]; size_t glA[2];
  int ldsB[2][2]; size_t glB[2][2];
#pragma unroll
  for (int rd = 0; rd < 2; rd++) {
    int j = tid + rd * 512, rp = j >> 3, s = j & 7;
    int cl = (s ^ (rp & 7)) * 8;
    ldsA[rd] = rp * 64 + s * 8;
    glA[rd]  = (size_t)(m0 + rp) * 1024 + cl;
#pragma unroll
    for (int nh = 0; nh < 2; nh++) {
      int cc = (rp & 31) + nh * 32 + (rp >> 5) * 64;
      ldsB[nh][rd] = cc * 64 + s * 8;
      glB[nh][rd]  = (size_t)(n0 + cc) * 1024 + cl;
    }
  }

#if HAVE_GLL
#define G8(g, l) gload_lds16((g), (l))
#else
#define G8(g, l) (*(uint4*)(l) = *(const uint4*)(g))
#endif
#define STG_A(t, bf)                                                       \
  if ((t) < NT_K) {                                                        \
    _Pragma("unroll") for (int rd = 0; rd < 2; rd++)                       \
      G8(A + glA[rd] + (t) * 64, As + (bf) * 8192 + ldsA[rd]);             \
  }
#define STG_B(nh, t, bf)                                                   \
  if ((t) < NT_K) {                                                        \
    _Pragma("unroll") for (int rd = 0; rd < 2; rd++)                       \
      G8(Bt + glB[nh][rd] + (t) * 64, Bs + (bf) * 16384 + ldsB[nh][rd]);   \
  }

  const int ck0  = ((quad)     ^ (l16 & 7)) * 8;
  const int ck1  = ((4 + quad) ^ (l16 & 7)) * 8;
  const int arow = (wm * 64 + l16) * 64;
  const int brow = (wn * 64 + l16) * 64;

  f32x4 acc[4][4];
#pragma unroll
  for (int i = 0; i < 4; i++)
#pragma unroll
    for (int j = 0; j < 4; j++) acc[i][j] = (f32x4){0.f, 0.f, 0.f, 0.f};

  short8 af[4][2], bA[2][2], bB[2][2];

#define READ_A(cur)                                                        \
  { const u16* pa = As + (cur) * 8192 + arow;                              \
    _Pragma("unroll") for (int m = 0; m < 4; m++) {                        \
      af[m][0] = *(const short8*)(pa + m * 1024 + ck0);                    \
      af[m][1] = *(const short8*)(pa + m * 1024 + ck1); } }
#define READ_B(dst, nh, cur)                                               \
  { const u16* pb = Bs + (cur) * 16384 + brow + (nh) * 2048;               \
    _Pragma("unroll") for (int n = 0; n < 2; n++) {                        \
      dst[n][0] = *(const short8*)(pb + n * 1024 + ck0);                   \
      dst[n][1] = *(const short8*)(pb + n * 1024 + ck1); } }
#define MM16(bfr, nh)                                                      \
  __builtin_amdgcn_s_setprio(1);                                           \
  _Pragma("unroll") for (int m = 0; m < 4; m++)                            \
    _Pragma("unroll") for (int n = 0; n < 2; n++) {                        \
      acc[m][(nh)*2+n] = __builtin_amdgcn_mfma_f32_16x16x32_bf16(          \
          af[m][0], bfr[n][0], acc[m][(nh)*2+n], 0, 0, 0);                 \
      acc[m][(nh)*2+n] = __builtin_amdgcn_mfma_f32_16x16x32_bf16(          \
          af[m][1], bfr[n][1], acc[m][(nh)*2+n], 0, 0, 0); }               \
  __builtin_amdgcn_s_setprio(0);
#define BARR { __builtin_amdgcn_s_barrier(); __builtin_amdgcn_sched_barrier(0); }

  STG_A(0, 0); STG_B(1, 0, 0); STG_B(0, 0, 0);
  STG_A(1, 1); STG_B(1, 1, 1); STG_B(0, 1, 1);
  asm volatile("s_waitcnt vmcnt(6)");
  BARR;

#pragma unroll
  for (int kt = 0; kt < NT_K; kt++) {
    const int cur = kt % 3;
    const int stb = (kt + 2) % 3;
    READ_A(cur); READ_B(bA, 0, cur);
    STG_A(kt + 2, stb); STG_B(1, kt + 2, stb);
    BARR;
    MM16(bA, 0);
    BARR;
    READ_B(bB, 1, cur);
    STG_B(0, kt + 2, stb);
    BARR;
    MM16(bB, 1);
    if (kt < NT_K - 2)       { asm volatile("s_waitcnt vmcnt(6)"); }
    else if (kt == NT_K - 2) { asm volatile("s_waitcnt vmcnt(0)"); }
    BARR;
  }
#undef STG_A
#undef STG_B
#undef READ_A
#undef READ_B
#undef MM16
#undef BARR
#undef G8

  float bvv[4];
#pragma unroll
  for (int ni = 0; ni < 4; ni++)
    bvv[ni] = bf2f(bias[n0 + wn * 64 + ni * 16 + l16]);

  if (!cf32) {
    u16* cs = smem + w * 4096;
#pragma unroll
    for (int m = 0; m < 4; m++)
#pragma unroll
      for (int ni = 0; ni < 4; ni++)
#pragma unroll
        for (int r = 0; r < 4; r++) {
          int row = m * 16 + quad * 4 + r;
          int ch  = ((ni * 2 + (l16 >> 3)) ^ (row & 7)) * 8 + (l16 & 7);
          cs[row * 64 + ch] = f2bf(acc[m][ni][r] + bvv[ni]);
        }
    u16* Cb = (u16*)C;
#pragma unroll
    for (int i = 0; i < 8; i++) {
      int ch = lane + i * 64;
      int rr = ch >> 3, cc = ch & 7;
      short8 v = *(const short8*)(cs + rr * 64 + ((cc ^ (rr & 7)) * 8));
      *(short8*)&Cb[(size_t)(m0 + wm * 64 + rr) * ldc + n0 + wn * 64 + cc * 8] = v;
    }
  } else {
    float* cf = (float*)(void*)smem + w * 2048;
#pragma unroll
    for (int pass = 0; pass < 2; pass++) {
#pragma unroll
      for (int m2 = 0; m2 < 2; m2++)
#pragma unroll
        for (int ni = 0; ni < 4; ni++)
#pragma unroll
          for (int r = 0; r < 4; r++) {
            int row = m2 * 16 + quad * 4 + r;
            int ch  = ((ni * 4 + (l16 >> 2)) ^ (row & 15)) * 4 + (l16 & 3);
            cf[row * 64 + ch] = acc[pass * 2 + m2][ni][r] + bvv[ni];
          }
      float* Cf = (float*)C;
#pragma unroll
      for (int i = 0; i < 8; i++) {
        int ch = lane + i * 64;
        int rr = ch >> 4, cc = ch & 15;
        f32x4 v = *(const f32x4*)(cf + rr * 64 + ((cc ^ (rr & 15)) * 4));
        *(f32x4*)&Cf[(size_t)(m0 + wm * 64 + pass * 32 + rr) * ldc +
                     n0 + wn * 64 + cc * 4] = v;
      }
    }
  }
}

// ---------------------------------------------------------------------------
// V transpose: Vt[(b*16+h)*64 + d][t] = P[b*T+t][vcol(h)+d]. 64x64 LDS tiles.
// ---------------------------------------------------------------------------
__global__ __launch_bounds__(256) void vt_kernel(const u16* __restrict__ P,
                                                 u16* __restrict__ Vt)
{
  const int tt = blockIdx.x * 64;
  const int bh = blockIdx.y;
  const int b = bh >> 4, h = bh & 15;
  const int vcol = 1552 + h * HEAD_DIM;
  __shared__ u16 t[64][65];
  const int tx = threadIdx.x & 63, ty = threadIdx.x >> 6;
#pragma unroll
  for (int rr = 0; rr < 16; rr++) {
    int r = ty * 16 + rr;
    t[r][tx] = P[((size_t)b * SEQ_T + tt + r) * PNS + vcol + tx];
  }
  __syncthreads();
#pragma unroll
  for (int rr = 0; rr < 16; rr++) {
    int d = ty * 16 + rr;
    Vt[((size_t)bh * 64 + d) * SEQ_T + tt + tx] = t[tx][d];
  }
}

// ---------------------------------------------------------------------------
// Causal flash attention, swapped 32x32 QK^T + in-register softmax (T12).
// ROUND 8, two changes:
// (1) FORCED permlane: round-7's SQ_LDS_BANK_CONFLICT was bit-identical to
//     round 6 (6,422,528) -> __has_builtin(permlane32_swap) must have been 0
//     and the ds_bpermute fallback silently ran. Now the fallback is RAW
//     inline asm v_permlane32_swap_b32 (gfx950 instruction; semantics
//     "A.lanes[32:63] <-> B.lanes[0:31]", per LLVM: one swap of (g0,g2)
//     yields A-frag words v0,v2; (g1,g3) yields v1,v3 - re-verified).
// (2) ADJACENT PAIRING: pairs (p, 31-p) cost 392 block-iters/bh while useful
//     chain-iters = 528/784 (the far B-chain drags a fully-masked A-chain
//     ~16 tiles/block). Pairs (2j, 2j+1): nkt = 2j+2, total 272 block-iters
//     (-30% iterations/staging/barriers); chain A fully masked for exactly
//     ONE iter. Imbalance (2..32 iters) is scheduler-backfilled (R4 vs R5
//     showed imbalance costs ~nothing at 1024 blocks). vmcnt ledger checked
//     for nkt=2 and nkt=4 edge cases (drain at kt=nkt-2, clean endpgm).
// Rest unchanged: LDS 48KB -> 3 blocks/CU; triple-buffer + counted vmcnt(4);
// 32x32 MFMAs; per-element mask at the two diagonal tiles.
// ---------------------------------------------------------------------------
__global__ __launch_bounds__(256, 3) void attn_kernel(
    const u16* __restrict__ P, const u16* __restrict__ Vt,
    u16* __restrict__ Y)
{
  const int bh  = blockIdx.x;
  const int b   = bh >> 4, h = bh & 15;
  const int j   = blockIdx.y;           // 0..15
  const int qtA = 2 * j, qtB = 2 * j + 1;
  const int tid = threadIdx.x;
  const int w   = tid >> 6;
  const int lane = tid & 63;
  const int l32 = lane & 31, hi = lane >> 5;
  const size_t rowb = (size_t)b * SEQ_T;
  const int qcol = 16 + h * PRIV;
  const int kcol = 784 + h * PRIV;

  __shared__ __align__(16) u16 Ks[3][64 * 64];     // [j][dchunk^(j&7)]
  __shared__ __align__(16) u16 Vs[3][64 * 64];     // [d][tchunk^(d&7)]

  const float csc = 0.18033688011112042f;  // (1/8)*log2(e)
  const int iA = qtA * 64 + w * 16, iB = qtB * 64 + w * 16;
  // per-lane q: cols 0-15 = chain A, 16-31 = chain B
  const int gi = (l32 < 16) ? (iA + l32) : (iB + l32 - 16);
  const u16* qptr = P + (rowb + gi) * PNS;

  // Q B-frag: chunk c holds d = 16c + 8hi + e (e=0..7)
  short8 qb[4];
  qb[0] = *(const short8*)&qptr[8 * hi];                       // share d 0..15
#pragma unroll
  for (int c = 1; c < 4; c++)
    qb[c] = *(const short8*)&qptr[qcol + 16 * c + 8 * hi - 16];// priv d 16..63
#pragma unroll
  for (int c = 0; c < 4; c++)
#pragma unroll
    for (int e = 0; e < 8; e++)
      qb[c][e] = (short)f2bf(bf2f((u16)qb[c][e]) * csc);

  short8 ones;
#pragma unroll
  for (int e = 0; e < 8; e++) ones[e] = (short)0x3F80;

  const int nkt = qtB + 1;   // 2j+2: ranges 2..32

#if HAVE_GLL
#define GLOADA(g, l) gload_lds16((g), (l))
#else
#define GLOADA(g, l) (*(uint4*)(l) = *(const uint4*)(g))
#endif
#define STAGE_KV(t, bb)                                                        \
  {                                                                            \
    const int kk0 = (t) * 64;                                                  \
    _Pragma("unroll") for (int i2 = 0; i2 < 2; i2++) {                         \
      int c   = tid + i2 * 256;                                                \
      int row = c >> 3;                                                        \
      int dg  = ((c & 7) ^ (row & 7)) * 8;                                     \
      int col = (dg < 16) ? dg : (kcol + dg - 16);                             \
      GLOADA(&P[(rowb + kk0 + row) * PNS + col], &Ks[bb][c * 8]);              \
      GLOADA(&Vt[((size_t)bh * 64 + row) * SEQ_T + kk0 + dg], &Vs[bb][c * 8]); \
    }                                                                          \
  }

  f32x16 accy[2], accl;
#pragma unroll
  for (int r = 0; r < 16; r++) { accy[0][r] = 0.f; accy[1][r] = 0.f; accl[r] = 0.f; }

  const float ninf = -__builtin_inff();

  // prologue: tiles 0,1 in flight; confirm 0, leave 1 outstanding
  STAGE_KV(0, 0);
  STAGE_KV(1, 1);
  asm volatile("s_waitcnt vmcnt(4)" ::: "memory");
  __builtin_amdgcn_sched_barrier(0);
  __builtin_amdgcn_s_barrier();

  for (int kt = 0; kt < nkt; kt++) {
    const int cur = kt % 3;
    const int k0  = kt * 64;
    if (kt + 2 < nkt) STAGE_KV(kt + 2, (kt + 2) % 3);   // 2-deep prefetch

#pragma unroll
    for (int kk = 0; kk < 2; kk++) {
      // ---- S^T = K @ Q : C[key=(r&3)+8(r>>2)+4hi][q=l32] ----
      f32x16 s;
#pragma unroll
      for (int r = 0; r < 16; r++) s[r] = 0.f;
      const int krow = kk * 32 + l32;
      __builtin_amdgcn_s_setprio(1);
#pragma unroll
      for (int c = 0; c < 4; c++) {
        short8 ka = *(const short8*)&Ks[cur][krow * 64 + (((2 * c + hi) ^ (krow & 7)) * 8)];
        s = __builtin_amdgcn_mfma_f32_32x32x16_bf16(ka, qb[c], s, 0, 0, 0);
      }
      __builtin_amdgcn_s_setprio(0);

      // ---- causal mask ----
      if (kt == qtA || kt == qtB) {
#pragma unroll
        for (int r = 0; r < 16; r++) {
          int gj = k0 + kk * 32 + (r & 3) + 8 * (r >> 2) + 4 * hi;
          if (gj > gi) s[r] = ninf;
        }
      }
      if (kt > qtA) {   // chain-A cols fully masked past their diagonal (1 iter)
#pragma unroll
        for (int r = 0; r < 16; r++)
          if (l32 < 16) s[r] = ninf;
      }

      // ---- p = exp2(s) ----
      float px[16];
#pragma unroll
      for (int r = 0; r < 16; r++) px[r] = EXP2(s[r]);

      // ---- per 16-key chunk: in-register P->A-frag, then rowsum + PV ----
#pragma unroll
      for (int kc = 0; kc < 2; kc++) {
        unsigned g0, g1, g2, g3;
        asm("v_cvt_pk_bf16_f32 %0, %1, %2" : "=v"(g0) : "v"(px[8*kc+0]), "v"(px[8*kc+1]));
        asm("v_cvt_pk_bf16_f32 %0, %1, %2" : "=v"(g1) : "v"(px[8*kc+2]), "v"(px[8*kc+3]));
        asm("v_cvt_pk_bf16_f32 %0, %1, %2" : "=v"(g2) : "v"(px[8*kc+4]), "v"(px[8*kc+5]));
        asm("v_cvt_pk_bf16_f32 %0, %1, %2" : "=v"(g3) : "v"(px[8*kc+6]), "v"(px[8*kc+7]));
        // lane H holds keys {16kc+4H+m} in g0/g1 and {16kc+8+4H+m} in g2/g3.
        // A-frag lane hi needs keys 16kc+8hi+{0..7}: own half + partner half.
#if HAVE_PLSWAP
        // permlane32_swap(a,b): new_a=[a(0:31) | b(0:31)->hi], new_b=[a(32:63)->lo | b(32:63)]
        uint2v r02 = __builtin_amdgcn_permlane32_swap(g0, g2, false, false);
        uint2v r13 = __builtin_amdgcn_permlane32_swap(g1, g3, false, false);
        uint32x4 pv = {r02.x, r13.x, r02.y, r13.y};
#else
        // raw asm: both operands updated in place.
        // new_g0[lane<32]=g0 own, [lane>=32]=g2 partner -> v0
        // new_g2[lane<32]=g0 partner, [lane>=32]=g2 own -> v2
        unsigned a0 = g0, b0 = g2, a1 = g1, b1 = g3;
        asm("v_permlane32_swap_b32 %0, %1" : "+v"(a0), "+v"(b0));
        asm("v_permlane32_swap_b32 %0, %1" : "+v"(a1), "+v"(b1));
        uint32x4 pv = {a0, a1, b0, b1};
#endif
        short8 pa = __builtin_bit_cast(short8, pv);

        __builtin_amdgcn_s_setprio(1);
        accl = __builtin_amdgcn_mfma_f32_32x32x16_bf16(pa, ones, accl, 0, 0, 0);
#pragma unroll
        for (int dt = 0; dt < 2; dt++) {
          int vrow = dt * 32 + l32;
          short8 vbf = *(const short8*)&Vs[cur][vrow * 64 + (((4*kk + 2*kc + hi) ^ (vrow & 7)) * 8)];
          accy[dt] = __builtin_amdgcn_mfma_f32_32x32x16_bf16(pa, vbf, accy[dt], 0, 0, 0);
        }
        __builtin_amdgcn_s_setprio(0);
      }
    }

    // counted bottom wait: keep next-next tile's 4 loads in flight
    if (kt + 3 < nkt) {
      asm volatile("s_waitcnt vmcnt(4)" ::: "memory");
      __builtin_amdgcn_sched_barrier(0);
      __builtin_amdgcn_s_barrier();
    } else if (kt + 2 == nkt) {       // kt == nkt-2: drain the last tile
      asm volatile("s_waitcnt vmcnt(0)" ::: "memory");
      __builtin_amdgcn_sched_barrier(0);
      __builtin_amdgcn_s_barrier();
    } else if (kt + 3 == nkt) {       // kt == nkt-3: confirm tile nkt-2
      asm volatile("s_waitcnt vmcnt(4)" ::: "memory");
      __builtin_amdgcn_sched_barrier(0);
      __builtin_amdgcn_s_barrier();
    }
    // kt == nkt-1: no wait, fall through to epilogue
  }
#undef STAGE_KV
#undef GLOADA

  // ---- epilogue: C[row=q][col=d]; q=(r&3)+8(r>>2)+4hi; r<8 -> chain A ----
  float inv[16];
#pragma unroll
  for (int r = 0; r < 16; r++) inv[r] = 1.0f / accl[r];
#pragma unroll
  for (int r = 0; r < 16; r++) {
    int q = (r & 3) + 8 * (r >> 2) + 4 * hi;
    int grow = (r < 8) ? (iA + q) : (iB + q - 16);
    size_t base = (rowb + grow) * N_EMBD + h * HEAD_DIM + l32;
    Y[base]      = f2bf(accy[0][r] * inv[r]);
    Y[base + 32] = f2bf(accy[1][r] * inv[r]);
  }
}

// ---------------------------------------------------------------------------
extern "C" void kernel_launch(void* const* d_in, const int* in_sizes, int n_in,
                              void* d_out, int out_size, void* d_ws, size_t ws_size,
                              hipStream_t stream) {
  (void)in_sizes; (void)n_in; (void)out_size; (void)ws_size;
  const void* x   = d_in[0];
  const void* Wsh = d_in[1];
  const void* bsh = d_in[2];
  const void* Wq  = d_in[3];
  const void* bq  = d_in[4];
  const void* Wk  = d_in[5];
  const void* bk  = d_in[6];
  const void* Wv  = d_in[7];
  const void* bv  = d_in[8];
  const void* Wo  = d_in[9];
  const void* bo  = d_in[10];

  char* wsb = (char*)d_ws;
  int* flag = (int*)wsb;
  u16* ws16 = (u16*)(wsb + 64);
  u16* Wcat = ws16;                                   // PNS*1024 (transposed)
  u16* bcat = Wcat + (size_t)PNS * N_EMBD;            // PNS
  u16* Woc  = bcat + PNS;                             // 1024*1024 (transposed)
  u16* boc  = Woc + (size_t)N_EMBD * N_EMBD;          // 1024
  u16* Pb   = boc + N_EMBD;                           // 8192*2816
  u16* Yb   = Pb + (size_t)M_ROWS * PNS;              // 8192*1024 (also Xb)
  u16* Vtb  = Yb + (size_t)M_ROWS * N_EMBD;           // 64*64*2048
  u16* Xb   = Yb;   // x->bf16 staging aliases Yb: proj reads Xb, attn writes Yb later

  detect_kernel<<<dim3(1), dim3(256), 0, stream>>>((const u16*)x, flag);
  pack_t_kernel<<<dim3(16, 16, 6), dim3(256), 0, stream>>>(
      Wsh, Wq, Wk, Wv, Wo, bsh, bq, bk, bv, bo, Wcat, Woc, bcat, boc, flag);
  xbf_kernel<<<dim3(M_ROWS * N_EMBD / (256 * 8)), dim3(256), 0, stream>>>(
      x, Xb, flag);
  // proj GEMM: [8192 x 2816] = Xb @ Wcat^T, bf16 out
  gemm8p_kernel<<<dim3(64 * (PNS / 256)), dim3(512), 0, stream>>>(
      Xb, Wcat, bcat, Pb, PNS, 64, flag, 0);
  vt_kernel<<<dim3(SEQ_T / 64, BATCH * N_HEADS), dim3(256), 0, stream>>>(
      Pb, Vtb);
  attn_kernel<<<dim3(BATCH * N_HEADS, NTILES / 2), dim3(256), 0, stream>>>(
      Pb, Vtb, Yb);
  // out GEMM: [8192 x 1024] = Yb @ Woc^T, f32 out when inputs were f32
  gemm8p_kernel<<<dim3(64 * (N_EMBD / 256)), dim3(512), 0, stream>>>(
      Yb, Woc, boc, d_out, N_EMBD, 64, flag, 1);
}

// Round 9
// 261.026 us; speedup vs baseline: 1.1513x; 1.0545x over previous
//
#include <hip/hip_runtime.h>
#include <hip/hip_bf16.h>

typedef unsigned short u16;
typedef short short8 __attribute__((ext_vector_type(8)));
typedef float f32x4 __attribute__((ext_vector_type(4)));
typedef float f32x16 __attribute__((ext_vector_type(16)));
typedef unsigned uint32x4 __attribute__((ext_vector_type(4)));

#define N_EMBD   1024
#define N_HEADS  16
#define HEAD_DIM 64
#define PRIV     48
#define SEQ_T    2048
#define BATCH    4
#define M_ROWS   (BATCH*SEQ_T)   // 8192
// Packed proj layout (round 9): [share 16 | pad 48 | q 768 | k 768 | v 1024 | pad]
//   share@0, q@64, k@832, v@1600 (64-ALIGNED so one GEMM wave = one head), end 2624 -> pad to 2816.
#define PNS      2816
#define QOFF     64
#define KOFF     832
#define VOFF     1600
#define NTILES   (SEQ_T/64)      // 32
#define NT_K     16              // K=1024 / BK=64

#if __has_builtin(__builtin_amdgcn_exp2f)
#define EXP2(x) __builtin_amdgcn_exp2f(x)
#else
#define EXP2(x) exp2f(x)
#endif

#if __has_builtin(__builtin_amdgcn_global_load_lds)
#define HAVE_GLL 1
#else
#define HAVE_GLL 0
#endif

#if __has_builtin(__builtin_amdgcn_permlane32_swap)
#define HAVE_PLSWAP 1
typedef unsigned uint2v __attribute__((ext_vector_type(2)));
#else
#define HAVE_PLSWAP 0
#endif

__device__ __forceinline__ u16 f2bf(float f) {
  __hip_bfloat16 h = __float2bfloat16(f);
  return *reinterpret_cast<u16*>(&h);
}
__device__ __forceinline__ float bf2f(u16 s) {
  __hip_bfloat16 h;
  *reinterpret_cast<u16*>(&h) = s;
  return __bfloat162float(h);
}
__device__ __forceinline__ float loadv(const void* p, size_t i, int isf32) {
  return isf32 ? ((const float*)p)[i] : bf2f(((const u16*)p)[i]);
}
__device__ __forceinline__ u16 truncbf(float f) {
  unsigned u = __builtin_bit_cast(unsigned, f);
  return (u16)(u >> 16);
}
#if HAVE_GLL
__device__ __forceinline__ void gload_lds16(const u16* g, u16* l) {
  __builtin_amdgcn_global_load_lds(
      (const __attribute__((address_space(1))) void*)g,
      (__attribute__((address_space(3))) void*)l, 16, 0, 0);
}
#endif

// ---------------------------------------------------------------------------
// Dtype detector (1 = f32 inputs).
// ---------------------------------------------------------------------------
__global__ __launch_bounds__(256) void detect_kernel(const u16* __restrict__ x,
                                                     int* __restrict__ flag) {
  __shared__ int cnt;
  if (threadIdx.x == 0) cnt = 0;
  __syncthreads();
  u16 v = x[2 * threadIdx.x];
  int e = (v >> 7) & 0xFF;
  int junk = (e >= 0xC0 || (e != 0 && e <= 0x30)) ? 1 : 0;
  if (junk) atomicAdd(&cnt, 1);
  __syncthreads();
  if (threadIdx.x == 0) *flag = (cnt > 16) ? 1 : 0;
}

// ---------------------------------------------------------------------------
// Transposing pack (weights -> [n][k] bf16) + z=5 slice does zero-pad + biases.
// Round-9 layout: share@0, q@64, k@832, v@1600; pad rows 16..63 & 2624..2815.
// ---------------------------------------------------------------------------
__global__ __launch_bounds__(256) void pack_t_kernel(
    const void* __restrict__ Wsh, const void* __restrict__ Wq,
    const void* __restrict__ Wk,  const void* __restrict__ Wv,
    const void* __restrict__ Wo,
    const void* __restrict__ bsh, const void* __restrict__ bq,
    const void* __restrict__ bk,  const void* __restrict__ bv,
    const void* __restrict__ bo,
    u16* __restrict__ Wcat, u16* __restrict__ Woc,
    u16* __restrict__ bcat, u16* __restrict__ boc,
    const int* __restrict__ flagp)
{
  const int f = *flagp;
  if (blockIdx.z == 5) {  // pad + biases
    const int flat = blockIdx.y * 16 + blockIdx.x;
    const int padRows = 48 + 192;   // rows 16..63 and 2624..2815
    for (int i = flat * 256 + threadIdx.x; i < padRows * 1024; i += 256 * 256) {
      int r = i >> 10, c2 = i & 1023;
      int row = (r < 48) ? (16 + r) : (2624 + (r - 48));
      Wcat[(size_t)row * 1024 + c2] = 0;
    }
    if (flat == 0) {
      for (int c = threadIdx.x; c < PNS; c += 256) {
        float v = 0.f;
        if (c < 16)         v = loadv(bsh, c, f);
        else if (c < QOFF)  v = 0.f;
        else if (c < KOFF)  v = loadv(bq, c - QOFF, f);
        else if (c < VOFF)  v = loadv(bk, c - KOFF, f);
        else if (c < 2624)  v = loadv(bv, c - VOFF, f);
        bcat[c] = f2bf(v);
      }
    } else if (flat == 1) {
      for (int c = threadIdx.x; c < N_EMBD; c += 256)
        boc[c] = f2bf(loadv(bo, c, f));
    }
    return;
  }
  const void* src; u16* dst; int N, rowOff;
  switch (blockIdx.z) {
    case 0: src = Wsh; dst = Wcat; N = 16;   rowOff = 0;    break;
    case 1: src = Wq;  dst = Wcat; N = 768;  rowOff = QOFF; break;
    case 2: src = Wk;  dst = Wcat; N = 768;  rowOff = KOFF; break;
    case 3: src = Wv;  dst = Wcat; N = 1024; rowOff = VOFF; break;
    default:src = Wo;  dst = Woc;  N = 1024; rowOff = 0;    break;
  }
  const int n0 = blockIdx.x * 64;
  if (n0 >= N) return;
  const int k0 = blockIdx.y * 64;
  __shared__ u16 t[64][65];
  const int tx = threadIdx.x & 63, ty = threadIdx.x >> 6;
#pragma unroll
  for (int rr = 0; rr < 16; rr++) {
    int k = k0 + ty * 16 + rr;
    int n = n0 + tx;
    float v = (n < N) ? loadv(src, (size_t)k * N + n, f) : 0.f;
    t[ty * 16 + rr][tx] = f2bf(v);
  }
  __syncthreads();
#pragma unroll
  for (int rr = 0; rr < 16; rr++) {
    int n = ty * 16 + rr;
    if (n0 + n < N)
      dst[(size_t)(rowOff + n0 + n) * 1024 + k0 + tx] = t[tx][n];
  }
}

// ---------------------------------------------------------------------------
// x (f32 or bf16 per flag) -> Xb bf16 [8192][1024]. 8 elems/thread.
// ---------------------------------------------------------------------------
__global__ __launch_bounds__(256) void xbf_kernel(const void* __restrict__ x,
                                                  u16* __restrict__ Xb,
                                                  const int* __restrict__ flagp) {
  const int f = *flagp;
  const size_t i = (size_t)blockIdx.x * 256 + threadIdx.x;
  if (f) {
    const float4* p = (const float4*)x;
    float4 a = p[i * 2], b = p[i * 2 + 1];
    u16 t[8] = {f2bf(a.x), f2bf(a.y), f2bf(a.z), f2bf(a.w),
                f2bf(b.x), f2bf(b.y), f2bf(b.z), f2bf(b.w)};
    *(uint4*)&Xb[i * 8] = *(const uint4*)t;
  } else {
    *(uint4*)&Xb[i * 8] = ((const uint4*)x)[i];
  }
}

// ---------------------------------------------------------------------------
// 8-wave deep-pipelined bf16 GEMM: C(MxN) = A(MxK=1024) @ Bt(NxK)^T + bias.
// Tile BM=128 x BN=256, BK=64. Triple-buffered LDS; counted vmcnt(6) (T3+T4);
// T2 XOR swizzle; T5 setprio.
// ROUND 9: fused V-transpose epilogue. When vt_en and the wave's 64-col slice
// lies in [VOFF, VOFF+1024) (64-aligned = exactly one head), acc is stored
// TRANSPOSED into the per-wave LDS slice (cs_t[d][t], chunk-XOR swizzled, same
// 64-scalar-write count as the normal path) and emitted as 16B Vt[d][t] rows.
// Deletes the standalone vt_kernel (67 MB of transpose traffic).
// ---------------------------------------------------------------------------
__global__ __launch_bounds__(512, 2) void gemm8p_kernel(
    const u16* __restrict__ A,    // [M][1024] bf16
    const u16* __restrict__ Bt,   // [N][1024] bf16
    const u16* __restrict__ bias, // [N] bf16
    void* __restrict__ C, int ldc, int Mtiles,
    const int* __restrict__ flagp, int c_dyn,
    u16* __restrict__ VtOut, int vt_en)
{
  __shared__ __align__(16) u16 smem[73728];   // 147456 B
  u16* const As = smem;                       // 3 x [128*64]
  u16* const Bs = smem + 3 * 8192;            // 3 x [256*64]

  const bool cf32 = (c_dyn != 0) && (*flagp != 0);

  const int tid  = threadIdx.x;
  const int lane = tid & 63;
  const int w    = tid >> 6;
  const int quad = lane >> 4, l16 = lane & 15;
  const int wm   = w >> 2, wn = w & 3;

  const int nwg = gridDim.x;
  const int wg  = (blockIdx.x & 7) * (nwg >> 3) + (blockIdx.x >> 3);
  const int mb  = wg % Mtiles, nb = wg / Mtiles;
  const int m0  = mb * 128, n0 = nb * 256;

  int ldsA[2]; size_t glA[2];
  int ldsB[2][2]; size_t glB[2][2];
#pragma unroll
  for (int rd = 0; rd < 2; rd++) {
    int j = tid + rd * 512, rp = j >> 3, s = j & 7;
    int cl = (s ^ (rp & 7)) * 8;
    ldsA[rd] = rp * 64 + s * 8;
    glA[rd]  = (size_t)(m0 + rp) * 1024 + cl;
#pragma unroll
    for (int nh = 0; nh < 2; nh++) {
      int cc = (rp & 31) + nh * 32 + (rp >> 5) * 64;
      ldsB[nh][rd] = cc * 64 + s * 8;
      glB[nh][rd]  = (size_t)(n0 + cc) * 1024 + cl;
    }
  }

#if HAVE_GLL
#define G8(g, l) gload_lds16((g), (l))
#else
#define G8(g, l) (*(uint4*)(l) = *(const uint4*)(g))
#endif
#define STG_A(t, bf)                                                       \
  if ((t) < NT_K) {                                                        \
    _Pragma("unroll") for (int rd = 0; rd < 2; rd++)                       \
      G8(A + glA[rd] + (t) * 64, As + (bf) * 8192 + ldsA[rd]);             \
  }
#define STG_B(nh, t, bf)                                                   \
  if ((t) < NT_K) {                                                        \
    _Pragma("unroll") for (int rd = 0; rd < 2; rd++)                       \
      G8(Bt + glB[nh][rd] + (t) * 64, Bs + (bf) * 16384 + ldsB[nh][rd]);   \
  }

  const int ck0  = ((quad)     ^ (l16 & 7)) * 8;
  const int ck1  = ((4 + quad) ^ (l16 & 7)) * 8;
  const int arow = (wm * 64 + l16) * 64;
  const int brow = (wn * 64 + l16) * 64;

  f32x4 acc[4][4];
#pragma unroll
  for (int i = 0; i < 4; i++)
#pragma unroll
    for (int j = 0; j < 4; j++) acc[i][j] = (f32x4){0.f, 0.f, 0.f, 0.f};

  short8 af[4][2], bA[2][2], bB[2][2];

#define READ_A(cur)                                                        \
  { const u16* pa = As + (cur) * 8192 + arow;                              \
    _Pragma("unroll") for (int m = 0; m < 4; m++) {                        \
      af[m][0] = *(const short8*)(pa + m * 1024 + ck0);                    \
      af[m][1] = *(const short8*)(pa + m * 1024 + ck1); } }
#define READ_B(dst, nh, cur)                                               \
  { const u16* pb = Bs + (cur) * 16384 + brow + (nh) * 2048;               \
    _Pragma("unroll") for (int n = 0; n < 2; n++) {                        \
      dst[n][0] = *(const short8*)(pb + n * 1024 + ck0);                   \
      dst[n][1] = *(const short8*)(pb + n * 1024 + ck1); } }
#define MM16(bfr, nh)                                                      \
  __builtin_amdgcn_s_setprio(1);                                           \
  _Pragma("unroll") for (int m = 0; m < 4; m++)                            \
    _Pragma("unroll") for (int n = 0; n < 2; n++) {                        \
      acc[m][(nh)*2+n] = __builtin_amdgcn_mfma_f32_16x16x32_bf16(          \
          af[m][0], bfr[n][0], acc[m][(nh)*2+n], 0, 0, 0);                 \
      acc[m][(nh)*2+n] = __builtin_amdgcn_mfma_f32_16x16x32_bf16(          \
          af[m][1], bfr[n][1], acc[m][(nh)*2+n], 0, 0, 0); }               \
  __builtin_amdgcn_s_setprio(0);
#define BARR { __builtin_amdgcn_s_barrier(); __builtin_amdgcn_sched_barrier(0); }

  STG_A(0, 0); STG_B(1, 0, 0); STG_B(0, 0, 0);
  STG_A(1, 1); STG_B(1, 1, 1); STG_B(0, 1, 1);
  asm volatile("s_waitcnt vmcnt(6)");
  BARR;

#pragma unroll
  for (int kt = 0; kt < NT_K; kt++) {
    const int cur = kt % 3;
    const int stb = (kt + 2) % 3;
    READ_A(cur); READ_B(bA, 0, cur);
    STG_A(kt + 2, stb); STG_B(1, kt + 2, stb);
    BARR;
    MM16(bA, 0);
    BARR;
    READ_B(bB, 1, cur);
    STG_B(0, kt + 2, stb);
    BARR;
    MM16(bB, 1);
    if (kt < NT_K - 2)       { asm volatile("s_waitcnt vmcnt(6)"); }
    else if (kt == NT_K - 2) { asm volatile("s_waitcnt vmcnt(0)"); }
    BARR;
  }
#undef STG_A
#undef STG_B
#undef READ_A
#undef READ_B
#undef MM16
#undef BARR
#undef G8

  __syncthreads();   // cs slices overlap As/Bs buf0; make LDS reuse safe

  float bvv[4];
#pragma unroll
  for (int ni = 0; ni < 4; ni++)
    bvv[ni] = bf2f(bias[n0 + wn * 64 + ni * 16 + l16]);

  const int ncol0 = n0 + wn * 64;
  if (vt_en && ncol0 >= VOFF && ncol0 < VOFF + 1024) {
    // ---- fused V-transpose epilogue: acc -> cs_t[d][t] (swizzled) -> Vt ----
    u16* cs = smem + w * 4096;          // 64(d) x 64(t) bf16 per wave
#pragma unroll
    for (int m = 0; m < 4; m++)
#pragma unroll
      for (int ni = 0; ni < 4; ni++)
#pragma unroll
        for (int r = 0; r < 4; r++) {
          int d  = ni * 16 + l16;
          int tc = m * 2 + (quad >> 1);          // t>>3
          int te = (quad & 1) * 4 + r;           // t&7
          cs[d * 64 + ((tc ^ (d & 7)) * 8) + te] = f2bf(acc[m][ni][r] + bvv[ni]);
        }
    const int bb = (m0 + wm * 64) >> 11;
    const int t0 = (m0 + wm * 64) & 2047;
    const int hh = (ncol0 - VOFF) >> 6;
    __builtin_amdgcn_s_barrier();   // wave-local cs, but cheap ordering fence
#pragma unroll
    for (int i = 0; i < 8; i++) {
      int ch = lane + i * 64;
      int rr = ch >> 3, cc = ch & 7;   // rr = d, cc = t-chunk
      short8 v = *(const short8*)(cs + rr * 64 + ((cc ^ (rr & 7)) * 8));
      *(short8*)&VtOut[((size_t)(bb * 16 + hh) * 64 + rr) * SEQ_T + t0 + cc * 8] = v;
    }
  } else if (!cf32) {
    u16* cs = smem + w * 4096;
#pragma unroll
    for (int m = 0; m < 4; m++)
#pragma unroll
      for (int ni = 0; ni < 4; ni++)
#pragma unroll
        for (int r = 0; r < 4; r++) {
          int row = m * 16 + quad * 4 + r;
          int ch  = ((ni * 2 + (l16 >> 3)) ^ (row & 7)) * 8 + (l16 & 7);
          cs[row * 64 + ch] = f2bf(acc[m][ni][r] + bvv[ni]);
        }
    u16* Cb = (u16*)C;
#pragma unroll
    for (int i = 0; i < 8; i++) {
      int ch = lane + i * 64;
      int rr = ch >> 3, cc = ch & 7;
      short8 v = *(const short8*)(cs + rr * 64 + ((cc ^ (rr & 7)) * 8));
      *(short8*)&Cb[(size_t)(m0 + wm * 64 + rr) * ldc + n0 + wn * 64 + cc * 8] = v;
    }
  } else {
    float* cf = (float*)(void*)smem + w * 2048;
#pragma unroll
    for (int pass = 0; pass < 2; pass++) {
#pragma unroll
      for (int m2 = 0; m2 < 2; m2++)
#pragma unroll
        for (int ni = 0; ni < 4; ni++)
#pragma unroll
          for (int r = 0; r < 4; r++) {
            int row = m2 * 16 + quad * 4 + r;
            int ch  = ((ni * 4 + (l16 >> 2)) ^ (row & 15)) * 4 + (l16 & 3);
            cf[row * 64 + ch] = acc[pass * 2 + m2][ni][r] + bvv[ni];
          }
      float* Cf = (float*)C;
#pragma unroll
      for (int i = 0; i < 8; i++) {
        int ch = lane + i * 64;
        int rr = ch >> 4, cc = ch & 15;
        f32x4 v = *(const f32x4*)(cf + rr * 64 + ((cc ^ (rr & 15)) * 4));
        *(f32x4*)&Cf[(size_t)(m0 + wm * 64 + pass * 32 + rr) * ldc +
                     n0 + wn * 64 + cc * 4] = v;
      }
    }
  }
}

// ---------------------------------------------------------------------------
// Causal flash attention, swapped 32x32 QK^T + in-register softmax (T12).
// ROUND 9: (a) col remap for the new packed layout (qcol=64+h*48,
// kcol=832+h*48; V now read only from Vt, produced by the fused GEMM
// epilogue -- vt_kernel deleted); (b) HEAVY-FIRST scheduling j=15-blockIdx.y
// (adjacent pairs (2j,2j+1), nkt=2j+2 in 2..32: launching 32-iter blocks
// first lets the light blocks backfill the tail; R8 occupancy was 18%).
// Note (R8 post-mortem): the 256 conflict-cyc/block-iter are from the 32x32
// K/V ds_read pattern, NOT the lane exchange (identical count across
// shfl/permlane variants). permlane asm kept (fewer VALU ops either way).
// ---------------------------------------------------------------------------
__global__ __launch_bounds__(256, 3) void attn_kernel(
    const u16* __restrict__ P, const u16* __restrict__ Vt,
    u16* __restrict__ Y)
{
  const int bh  = blockIdx.x;
  const int b   = bh >> 4, h = bh & 15;
  const int j   = 15 - blockIdx.y;      // heavy-first
  const int qtA = 2 * j, qtB = 2 * j + 1;
  const int tid = threadIdx.x;
  const int w   = tid >> 6;
  const int lane = tid & 63;
  const int l32 = lane & 31, hi = lane >> 5;
  const size_t rowb = (size_t)b * SEQ_T;
  const int qcol = QOFF + h * PRIV;
  const int kcol = KOFF + h * PRIV;

  __shared__ __align__(16) u16 Ks[3][64 * 64];     // [j][dchunk^(j&7)]
  __shared__ __align__(16) u16 Vs[3][64 * 64];     // [d][tchunk^(d&7)]

  const float csc = 0.18033688011112042f;  // (1/8)*log2(e)
  const int iA = qtA * 64 + w * 16, iB = qtB * 64 + w * 16;
  // per-lane q: cols 0-15 = chain A, 16-31 = chain B
  const int gi = (l32 < 16) ? (iA + l32) : (iB + l32 - 16);
  const u16* qptr = P + (rowb + gi) * PNS;

  // Q B-frag: chunk c holds d = 16c + 8hi + e (e=0..7)
  short8 qb[4];
  qb[0] = *(const short8*)&qptr[8 * hi];                       // share d 0..15
#pragma unroll
  for (int c = 1; c < 4; c++)
    qb[c] = *(const short8*)&qptr[qcol + 16 * c + 8 * hi - 16];// priv d 16..63
#pragma unroll
  for (int c = 0; c < 4; c++)
#pragma unroll
    for (int e = 0; e < 8; e++)
      qb[c][e] = (short)f2bf(bf2f((u16)qb[c][e]) * csc);

  short8 ones;
#pragma unroll
  for (int e = 0; e < 8; e++) ones[e] = (short)0x3F80;

  const int nkt = qtB + 1;   // 2j+2: ranges 2..32

#if HAVE_GLL
#define GLOADA(g, l) gload_lds16((g), (l))
#else
#define GLOADA(g, l) (*(uint4*)(l) = *(const uint4*)(g))
#endif
#define STAGE_KV(t, bb)                                                        \
  {                                                                            \
    const int kk0 = (t) * 64;                                                  \
    _Pragma("unroll") for (int i2 = 0; i2 < 2; i2++) {                         \
      int c   = tid + i2 * 256;                                                \
      int row = c >> 3;                                                        \
      int dg  = ((c & 7) ^ (row & 7)) * 8;                                     \
      int col = (dg < 16) ? dg : (kcol + dg - 16);                             \
      GLOADA(&P[(rowb + kk0 + row) * PNS + col], &Ks[bb][c * 8]);              \
      GLOADA(&Vt[((size_t)bh * 64 + row) * SEQ_T + kk0 + dg], &Vs[bb][c * 8]); \
    }                                                                          \
  }

  f32x16 accy[2], accl;
#pragma unroll
  for (int r = 0; r < 16; r++) { accy[0][r] = 0.f; accy[1][r] = 0.f; accl[r] = 0.f; }

  const float ninf = -__builtin_inff();

  // prologue: tiles 0,1 in flight; confirm 0, leave 1 outstanding
  STAGE_KV(0, 0);
  STAGE_KV(1, 1);
  asm volatile("s_waitcnt vmcnt(4)" ::: "memory");
  __builtin_amdgcn_sched_barrier(0);
  __builtin_amdgcn_s_barrier();

  for (int kt = 0; kt < nkt; kt++) {
    const int cur = kt % 3;
    const int k0  = kt * 64;
    if (kt + 2 < nkt) STAGE_KV(kt + 2, (kt + 2) % 3);   // 2-deep prefetch

#pragma unroll
    for (int kk = 0; kk < 2; kk++) {
      // ---- S^T = K @ Q : C[key=(r&3)+8(r>>2)+4hi][q=l32] ----
      f32x16 s;
#pragma unroll
      for (int r = 0; r < 16; r++) s[r] = 0.f;
      const int krow = kk * 32 + l32;
      __builtin_amdgcn_s_setprio(1);
#pragma unroll
      for (int c = 0; c < 4; c++) {
        short8 ka = *(const short8*)&Ks[cur][krow * 64 + (((2 * c + hi) ^ (krow & 7)) * 8)];
        s = __builtin_amdgcn_mfma_f32_32x32x16_bf16(ka, qb[c], s, 0, 0, 0);
      }
      __builtin_amdgcn_s_setprio(0);

      // ---- causal mask ----
      if (kt == qtA || kt == qtB) {
#pragma unroll
        for (int r = 0; r < 16; r++) {
          int gj = k0 + kk * 32 + (r & 3) + 8 * (r >> 2) + 4 * hi;
          if (gj > gi) s[r] = ninf;
        }
      }
      if (kt > qtA) {   // chain-A cols fully masked past their diagonal (1 iter)
#pragma unroll
        for (int r = 0; r < 16; r++)
          if (l32 < 16) s[r] = ninf;
      }

      // ---- p = exp2(s) ----
      float px[16];
#pragma unroll
      for (int r = 0; r < 16; r++) px[r] = EXP2(s[r]);

      // ---- per 16-key chunk: in-register P->A-frag, then rowsum + PV ----
#pragma unroll
      for (int kc = 0; kc < 2; kc++) {
        unsigned g0, g1, g2, g3;
        asm("v_cvt_pk_bf16_f32 %0, %1, %2" : "=v"(g0) : "v"(px[8*kc+0]), "v"(px[8*kc+1]));
        asm("v_cvt_pk_bf16_f32 %0, %1, %2" : "=v"(g1) : "v"(px[8*kc+2]), "v"(px[8*kc+3]));
        asm("v_cvt_pk_bf16_f32 %0, %1, %2" : "=v"(g2) : "v"(px[8*kc+4]), "v"(px[8*kc+5]));
        asm("v_cvt_pk_bf16_f32 %0, %1, %2" : "=v"(g3) : "v"(px[8*kc+6]), "v"(px[8*kc+7]));
        // lane H holds keys {16kc+4H+m} in g0/g1 and {16kc+8+4H+m} in g2/g3.
        // A-frag lane hi needs keys 16kc+8hi+{0..7}: own half + partner half.
#if HAVE_PLSWAP
        uint2v r02 = __builtin_amdgcn_permlane32_swap(g0, g2, false, false);
        uint2v r13 = __builtin_amdgcn_permlane32_swap(g1, g3, false, false);
        uint32x4 pv = {r02.x, r13.x, r02.y, r13.y};
#else
        unsigned a0 = g0, b0 = g2, a1 = g1, b1 = g3;
        asm("v_permlane32_swap_b32 %0, %1" : "+v"(a0), "+v"(b0));
        asm("v_permlane32_swap_b32 %0, %1" : "+v"(a1), "+v"(b1));
        uint32x4 pv = {a0, a1, b0, b1};
#endif
        short8 pa = __builtin_bit_cast(short8, pv);

        __builtin_amdgcn_s_setprio(1);
        accl = __builtin_amdgcn_mfma_f32_32x32x16_bf16(pa, ones, accl, 0, 0, 0);
#pragma unroll
        for (int dt = 0; dt < 2; dt++) {
          int vrow = dt * 32 + l32;
          short8 vbf = *(const short8*)&Vs[cur][vrow * 64 + (((4*kk + 2*kc + hi) ^ (vrow & 7)) * 8)];
          accy[dt] = __builtin_amdgcn_mfma_f32_32x32x16_bf16(pa, vbf, accy[dt], 0, 0, 0);
        }
        __builtin_amdgcn_s_setprio(0);
      }
    }

    // counted bottom wait: keep next-next tile's 4 loads in flight
    if (kt + 3 < nkt) {
      asm volatile("s_waitcnt vmcnt(4)" ::: "memory");
      __builtin_amdgcn_sched_barrier(0);
      __builtin_amdgcn_s_barrier();
    } else if (kt + 2 == nkt) {       // kt == nkt-2: drain the last tile
      asm volatile("s_waitcnt vmcnt(0)" ::: "memory");
      __builtin_amdgcn_sched_barrier(0);
      __builtin_amdgcn_s_barrier();
    } else if (kt + 3 == nkt) {       // kt == nkt-3: confirm tile nkt-2
      asm volatile("s_waitcnt vmcnt(4)" ::: "memory");
      __builtin_amdgcn_sched_barrier(0);
      __builtin_amdgcn_s_barrier();
    }
    // kt == nkt-1: no wait, fall through to epilogue
  }
#undef STAGE_KV
#undef GLOADA

  // ---- epilogue: C[row=q][col=d]; q=(r&3)+8(r>>2)+4hi; r<8 -> chain A ----
  float inv[16];
#pragma unroll
  for (int r = 0; r < 16; r++) inv[r] = 1.0f / accl[r];
#pragma unroll
  for (int r = 0; r < 16; r++) {
    int q = (r & 3) + 8 * (r >> 2) + 4 * hi;
    int grow = (r < 8) ? (iA + q) : (iB + q - 16);
    size_t base = (rowb + grow) * N_EMBD + h * HEAD_DIM + l32;
    Y[base]      = f2bf(accy[0][r] * inv[r]);
    Y[base + 32] = f2bf(accy[1][r] * inv[r]);
  }
}

// ---------------------------------------------------------------------------
extern "C" void kernel_launch(void* const* d_in, const int* in_sizes, int n_in,
                              void* d_out, int out_size, void* d_ws, size_t ws_size,
                              hipStream_t stream) {
  (void)in_sizes; (void)n_in; (void)out_size; (void)ws_size;
  const void* x   = d_in[0];
  const void* Wsh = d_in[1];
  const void* bsh = d_in[2];
  const void* Wq  = d_in[3];
  const void* bq  = d_in[4];
  const void* Wk  = d_in[5];
  const void* bk  = d_in[6];
  const void* Wv  = d_in[7];
  const void* bv  = d_in[8];
  const void* Wo  = d_in[9];
  const void* bo  = d_in[10];

  char* wsb = (char*)d_ws;
  int* flag = (int*)wsb;
  u16* ws16 = (u16*)(wsb + 64);
  u16* Wcat = ws16;                                   // PNS*1024 (transposed)
  u16* bcat = Wcat + (size_t)PNS * N_EMBD;            // PNS
  u16* Woc  = bcat + PNS;                             // 1024*1024 (transposed)
  u16* boc  = Woc + (size_t)N_EMBD * N_EMBD;          // 1024
  u16* Pb   = boc + N_EMBD;                           // 8192*2816
  u16* Yb   = Pb + (size_t)M_ROWS * PNS;              // 8192*1024 (also Xb)
  u16* Vtb  = Yb + (size_t)M_ROWS * N_EMBD;           // 64*64*2048
  u16* Xb   = Yb;   // x->bf16 staging aliases Yb: proj reads Xb, attn writes Yb later

  detect_kernel<<<dim3(1), dim3(256), 0, stream>>>((const u16*)x, flag);
  pack_t_kernel<<<dim3(16, 16, 6), dim3(256), 0, stream>>>(
      Wsh, Wq, Wk, Wv, Wo, bsh, bq, bk, bv, bo, Wcat, Woc, bcat, boc, flag);
  xbf_kernel<<<dim3(M_ROWS * N_EMBD / (256 * 8)), dim3(256), 0, stream>>>(
      x, Xb, flag);
  // proj GEMM: [8192 x 2816] = Xb @ Wcat^T, bf16 out; V block -> Vtb transposed
  gemm8p_kernel<<<dim3(64 * (PNS / 256)), dim3(512), 0, stream>>>(
      Xb, Wcat, bcat, Pb, PNS, 64, flag, 0, Vtb, 1);
  attn_kernel<<<dim3(BATCH * N_HEADS, NTILES / 2), dim3(256), 0, stream>>>(
      Pb, Vtb, Yb);
  // out GEMM: [8192 x 1024] = Yb @ Woc^T, f32 out when inputs were f32
  gemm8p_kernel<<<dim3(64 * (N_EMBD / 256)), dim3(512), 0, stream>>>(
      Yb, Woc, boc, d_out, N_EMBD, 64, flag, 1, nullptr, 0);
}

// Round 10
// 258.199 us; speedup vs baseline: 1.1639x; 1.0109x over previous
//
#include <hip/hip_runtime.h>
#include <hip/hip_bf16.h>

typedef unsigned short u16;
typedef short short8 __attribute__((ext_vector_type(8)));
typedef float f32x4 __attribute__((ext_vector_type(4)));
typedef float f32x16 __attribute__((ext_vector_type(16)));
typedef unsigned uint32x4 __attribute__((ext_vector_type(4)));

#define N_EMBD   1024
#define N_HEADS  16
#define HEAD_DIM 64
#define PRIV     48
#define SEQ_T    2048
#define BATCH    4
#define M_ROWS   (BATCH*SEQ_T)   // 8192
// Packed proj layout: [share 16 | pad 48 | q 768 | k 768 | v 1024 | pad]
//   share@0, q@64, k@832, v@1600 (64-ALIGNED so one GEMM wave = one head), end 2624 -> pad to 2816.
#define PNS      2816
#define QOFF     64
#define KOFF     832
#define VOFF     1600
#define NTILES   (SEQ_T/64)      // 32
#define NT_K     16              // K=1024 / BK=64

#if __has_builtin(__builtin_amdgcn_exp2f)
#define EXP2(x) __builtin_amdgcn_exp2f(x)
#else
#define EXP2(x) exp2f(x)
#endif

#if __has_builtin(__builtin_amdgcn_global_load_lds)
#define HAVE_GLL 1
#else
#define HAVE_GLL 0
#endif

#if __has_builtin(__builtin_amdgcn_permlane32_swap)
#define HAVE_PLSWAP 1
typedef unsigned uint2v __attribute__((ext_vector_type(2)));
#else
#define HAVE_PLSWAP 0
#endif

__device__ __forceinline__ u16 f2bf(float f) {
  __hip_bfloat16 h = __float2bfloat16(f);
  return *reinterpret_cast<u16*>(&h);
}
__device__ __forceinline__ float bf2f(u16 s) {
  __hip_bfloat16 h;
  *reinterpret_cast<u16*>(&h) = s;
  return __bfloat162float(h);
}
__device__ __forceinline__ float loadv(const void* p, size_t i, int isf32) {
  return isf32 ? ((const float*)p)[i] : bf2f(((const u16*)p)[i]);
}
__device__ __forceinline__ u16 truncbf(float f) {
  unsigned u = __builtin_bit_cast(unsigned, f);
  return (u16)(u >> 16);
}
#if HAVE_GLL
__device__ __forceinline__ void gload_lds16(const u16* g, u16* l) {
  __builtin_amdgcn_global_load_lds(
      (const __attribute__((address_space(1))) void*)g,
      (__attribute__((address_space(3))) void*)l, 16, 0, 0);
}
#endif

// ---------------------------------------------------------------------------
// Dtype detector (1 = f32 inputs).
// ---------------------------------------------------------------------------
__global__ __launch_bounds__(256) void detect_kernel(const u16* __restrict__ x,
                                                     int* __restrict__ flag) {
  __shared__ int cnt;
  if (threadIdx.x == 0) cnt = 0;
  __syncthreads();
  u16 v = x[2 * threadIdx.x];
  int e = (v >> 7) & 0xFF;
  int junk = (e >= 0xC0 || (e != 0 && e <= 0x30)) ? 1 : 0;
  if (junk) atomicAdd(&cnt, 1);
  __syncthreads();
  if (threadIdx.x == 0) *flag = (cnt > 16) ? 1 : 0;
}

// ---------------------------------------------------------------------------
// Transposing pack (weights -> [n][k] bf16); z=5 pad+biases; z=6 = merged
// x->bf16 conversion (ROUND 10: ran as a separate xbf_kernel before; merging
// makes it CONCURRENT with the weight packing -> time ~ max instead of sum,
// and drops one launch gap).
// ---------------------------------------------------------------------------
__global__ __launch_bounds__(256) void pack_t_kernel(
    const void* __restrict__ Wsh, const void* __restrict__ Wq,
    const void* __restrict__ Wk,  const void* __restrict__ Wv,
    const void* __restrict__ Wo,
    const void* __restrict__ bsh, const void* __restrict__ bq,
    const void* __restrict__ bk,  const void* __restrict__ bv,
    const void* __restrict__ bo,
    u16* __restrict__ Wcat, u16* __restrict__ Woc,
    u16* __restrict__ bcat, u16* __restrict__ boc,
    const void* __restrict__ x, u16* __restrict__ Xb,
    const int* __restrict__ flagp)
{
  const int f = *flagp;
  if (blockIdx.z == 6) {  // merged x -> bf16 (8192x1024, 8 elems/group)
    const int flat = blockIdx.y * 16 + blockIdx.x;   // 0..255
#pragma unroll
    for (int it = 0; it < 16; it++) {
      size_t i = (size_t)flat * 4096 + it * 256 + threadIdx.x;
      if (f) {
        const float4* p = (const float4*)x;
        float4 a = p[i * 2], b = p[i * 2 + 1];
        u16 t[8] = {f2bf(a.x), f2bf(a.y), f2bf(a.z), f2bf(a.w),
                    f2bf(b.x), f2bf(b.y), f2bf(b.z), f2bf(b.w)};
        *(uint4*)&Xb[i * 8] = *(const uint4*)t;
      } else {
        *(uint4*)&Xb[i * 8] = ((const uint4*)x)[i];
      }
    }
    return;
  }
  if (blockIdx.z == 5) {  // pad + biases
    const int flat = blockIdx.y * 16 + blockIdx.x;
    const int padRows = 48 + 192;   // rows 16..63 and 2624..2815
    for (int i = flat * 256 + threadIdx.x; i < padRows * 1024; i += 256 * 256) {
      int r = i >> 10, c2 = i & 1023;
      int row = (r < 48) ? (16 + r) : (2624 + (r - 48));
      Wcat[(size_t)row * 1024 + c2] = 0;
    }
    if (flat == 0) {
      for (int c = threadIdx.x; c < PNS; c += 256) {
        float v = 0.f;
        if (c < 16)         v = loadv(bsh, c, f);
        else if (c < QOFF)  v = 0.f;
        else if (c < KOFF)  v = loadv(bq, c - QOFF, f);
        else if (c < VOFF)  v = loadv(bk, c - KOFF, f);
        else if (c < 2624)  v = loadv(bv, c - VOFF, f);
        bcat[c] = f2bf(v);
      }
    } else if (flat == 1) {
      for (int c = threadIdx.x; c < N_EMBD; c += 256)
        boc[c] = f2bf(loadv(bo, c, f));
    }
    return;
  }
  const void* src; u16* dst; int N, rowOff;
  switch (blockIdx.z) {
    case 0: src = Wsh; dst = Wcat; N = 16;   rowOff = 0;    break;
    case 1: src = Wq;  dst = Wcat; N = 768;  rowOff = QOFF; break;
    case 2: src = Wk;  dst = Wcat; N = 768;  rowOff = KOFF; break;
    case 3: src = Wv;  dst = Wcat; N = 1024; rowOff = VOFF; break;
    default:src = Wo;  dst = Woc;  N = 1024; rowOff = 0;    break;
  }
  const int n0 = blockIdx.x * 64;
  if (n0 >= N) return;
  const int k0 = blockIdx.y * 64;
  __shared__ u16 t[64][65];
  const int tx = threadIdx.x & 63, ty = threadIdx.x >> 6;
#pragma unroll
  for (int rr = 0; rr < 16; rr++) {
    int k = k0 + ty * 16 + rr;
    int n = n0 + tx;
    float v = (n < N) ? loadv(src, (size_t)k * N + n, f) : 0.f;
    t[ty * 16 + rr][tx] = f2bf(v);
  }
  __syncthreads();
#pragma unroll
  for (int rr = 0; rr < 16; rr++) {
    int n = ty * 16 + rr;
    if (n0 + n < N)
      dst[(size_t)(rowOff + n0 + n) * 1024 + k0 + tx] = t[tx][n];
  }
}

// ---------------------------------------------------------------------------
// 8-wave deep-pipelined bf16 GEMM: C(MxN) = A(MxK=1024) @ Bt(NxK)^T + bias.
// Tile BM=128 x BN=256, BK=64. Triple-buffered LDS; counted vmcnt(6) (T3+T4);
// T2 XOR swizzle; T5 setprio. Fused V-transpose epilogue (round 9).
// ROUND 10: L2-locality tile mapping. Old mapping had each XCD sweep ALL 64
// M-tiles per B-panel -> A working set 16.8MB >> 4MB XCD-L2 -> A re-fetched
// from HBM per panel (FETCH 104MB vs 23MB inputs). New: xcd owns an 8-row
// A-strip (8 x 256KB = 2MB, L2-resident) and sweeps panels against it:
//   mb = xcd*8 + (s&7), nb = s>>3   (bijective: 704=8*(8*11), 256=8*(8*4)).
// ---------------------------------------------------------------------------
__global__ __launch_bounds__(512, 2) void gemm8p_kernel(
    const u16* __restrict__ A,    // [M][1024] bf16
    const u16* __restrict__ Bt,   // [N][1024] bf16
    const u16* __restrict__ bias, // [N] bf16
    void* __restrict__ C, int ldc, int Mtiles,
    const int* __restrict__ flagp, int c_dyn,
    u16* __restrict__ VtOut, int vt_en)
{
  (void)Mtiles;
  __shared__ __align__(16) u16 smem[73728];   // 147456 B
  u16* const As = smem;                       // 3 x [128*64]
  u16* const Bs = smem + 3 * 8192;            // 3 x [256*64]

  const bool cf32 = (c_dyn != 0) && (*flagp != 0);

  const int tid  = threadIdx.x;
  const int lane = tid & 63;
  const int w    = tid >> 6;
  const int quad = lane >> 4, l16 = lane & 15;
  const int wm   = w >> 2, wn = w & 3;

  const int xcd = blockIdx.x & 7;
  const int s   = blockIdx.x >> 3;
  const int mb  = xcd * 8 + (s & 7);
  const int nb  = s >> 3;
  const int m0  = mb * 128, n0 = nb * 256;

  int ldsA[2]; size_t glA[2];
  int ldsB[2][2]; size_t glB[2][2];
#pragma unroll
  for (int rd = 0; rd < 2; rd++) {
    int j = tid + rd * 512, rp = j >> 3, sl = j & 7;
    int cl = (sl ^ (rp & 7)) * 8;
    ldsA[rd] = rp * 64 + sl * 8;
    glA[rd]  = (size_t)(m0 + rp) * 1024 + cl;
#pragma unroll
    for (int nh = 0; nh < 2; nh++) {
      int cc = (rp & 31) + nh * 32 + (rp >> 5) * 64;
      ldsB[nh][rd] = cc * 64 + sl * 8;
      glB[nh][rd]  = (size_t)(n0 + cc) * 1024 + cl;
    }
  }

#if HAVE_GLL
#define G8(g, l) gload_lds16((g), (l))
#else
#define G8(g, l) (*(uint4*)(l) = *(const uint4*)(g))
#endif
#define STG_A(t, bf)                                                       \
  if ((t) < NT_K) {                                                        \
    _Pragma("unroll") for (int rd = 0; rd < 2; rd++)                       \
      G8(A + glA[rd] + (t) * 64, As + (bf) * 8192 + ldsA[rd]);             \
  }
#define STG_B(nh, t, bf)                                                   \
  if ((t) < NT_K) {                                                        \
    _Pragma("unroll") for (int rd = 0; rd < 2; rd++)                       \
      G8(Bt + glB[nh][rd] + (t) * 64, Bs + (bf) * 16384 + ldsB[nh][rd]);   \
  }

  const int ck0  = ((quad)     ^ (l16 & 7)) * 8;
  const int ck1  = ((4 + quad) ^ (l16 & 7)) * 8;
  const int arow = (wm * 64 + l16) * 64;
  const int brow = (wn * 64 + l16) * 64;

  f32x4 acc[4][4];
#pragma unroll
  for (int i = 0; i < 4; i++)
#pragma unroll
    for (int j = 0; j < 4; j++) acc[i][j] = (f32x4){0.f, 0.f, 0.f, 0.f};

  short8 af[4][2], bA[2][2], bB[2][2];

#define READ_A(cur)                                                        \
  { const u16* pa = As + (cur) * 8192 + arow;                              \
    _Pragma("unroll") for (int m = 0; m < 4; m++) {                        \
      af[m][0] = *(const short8*)(pa + m * 1024 + ck0);                    \
      af[m][1] = *(const short8*)(pa + m * 1024 + ck1); } }
#define READ_B(dst, nh, cur)                                               \
  { const u16* pb = Bs + (cur) * 16384 + brow + (nh) * 2048;               \
    _Pragma("unroll") for (int n = 0; n < 2; n++) {                        \
      dst[n][0] = *(const short8*)(pb + n * 1024 + ck0);                   \
      dst[n][1] = *(const short8*)(pb + n * 1024 + ck1); } }
#define MM16(bfr, nh)                                                      \
  __builtin_amdgcn_s_setprio(1);                                           \
  _Pragma("unroll") for (int m = 0; m < 4; m++)                            \
    _Pragma("unroll") for (int n = 0; n < 2; n++) {                        \
      acc[m][(nh)*2+n] = __builtin_amdgcn_mfma_f32_16x16x32_bf16(          \
          af[m][0], bfr[n][0], acc[m][(nh)*2+n], 0, 0, 0);                 \
      acc[m][(nh)*2+n] = __builtin_amdgcn_mfma_f32_16x16x32_bf16(          \
          af[m][1], bfr[n][1], acc[m][(nh)*2+n], 0, 0, 0); }               \
  __builtin_amdgcn_s_setprio(0);
#define BARR { __builtin_amdgcn_s_barrier(); __builtin_amdgcn_sched_barrier(0); }

  STG_A(0, 0); STG_B(1, 0, 0); STG_B(0, 0, 0);
  STG_A(1, 1); STG_B(1, 1, 1); STG_B(0, 1, 1);
  asm volatile("s_waitcnt vmcnt(6)");
  BARR;

#pragma unroll
  for (int kt = 0; kt < NT_K; kt++) {
    const int cur = kt % 3;
    const int stb = (kt + 2) % 3;
    READ_A(cur); READ_B(bA, 0, cur);
    STG_A(kt + 2, stb); STG_B(1, kt + 2, stb);
    BARR;
    MM16(bA, 0);
    BARR;
    READ_B(bB, 1, cur);
    STG_B(0, kt + 2, stb);
    BARR;
    MM16(bB, 1);
    if (kt < NT_K - 2)       { asm volatile("s_waitcnt vmcnt(6)"); }
    else if (kt == NT_K - 2) { asm volatile("s_waitcnt vmcnt(0)"); }
    BARR;
  }
#undef STG_A
#undef STG_B
#undef READ_A
#undef READ_B
#undef MM16
#undef BARR
#undef G8

  __syncthreads();   // cs slices overlap As/Bs buf0; make LDS reuse safe

  float bvv[4];
#pragma unroll
  for (int ni = 0; ni < 4; ni++)
    bvv[ni] = bf2f(bias[n0 + wn * 64 + ni * 16 + l16]);

  const int ncol0 = n0 + wn * 64;
  if (vt_en && ncol0 >= VOFF && ncol0 < VOFF + 1024) {
    // ---- fused V-transpose epilogue: acc -> cs_t[d][t] (swizzled) -> Vt ----
    u16* cs = smem + w * 4096;          // 64(d) x 64(t) bf16 per wave
#pragma unroll
    for (int m = 0; m < 4; m++)
#pragma unroll
      for (int ni = 0; ni < 4; ni++)
#pragma unroll
        for (int r = 0; r < 4; r++) {
          int d  = ni * 16 + l16;
          int tc = m * 2 + (quad >> 1);          // t>>3
          int te = (quad & 1) * 4 + r;           // t&7
          cs[d * 64 + ((tc ^ (d & 7)) * 8) + te] = f2bf(acc[m][ni][r] + bvv[ni]);
        }
    const int bb = (m0 + wm * 64) >> 11;
    const int t0 = (m0 + wm * 64) & 2047;
    const int hh = (ncol0 - VOFF) >> 6;
    __builtin_amdgcn_s_barrier();   // wave-local cs, but cheap ordering fence
#pragma unroll
    for (int i = 0; i < 8; i++) {
      int ch = lane + i * 64;
      int rr = ch >> 3, cc = ch & 7;   // rr = d, cc = t-chunk
      short8 v = *(const short8*)(cs + rr * 64 + ((cc ^ (rr & 7)) * 8));
      *(short8*)&VtOut[((size_t)(bb * 16 + hh) * 64 + rr) * SEQ_T + t0 + cc * 8] = v;
    }
  } else if (!cf32) {
    u16* cs = smem + w * 4096;
#pragma unroll
    for (int m = 0; m < 4; m++)
#pragma unroll
      for (int ni = 0; ni < 4; ni++)
#pragma unroll
        for (int r = 0; r < 4; r++) {
          int row = m * 16 + quad * 4 + r;
          int ch  = ((ni * 2 + (l16 >> 3)) ^ (row & 7)) * 8 + (l16 & 7);
          cs[row * 64 + ch] = f2bf(acc[m][ni][r] + bvv[ni]);
        }
    u16* Cb = (u16*)C;
#pragma unroll
    for (int i = 0; i < 8; i++) {
      int ch = lane + i * 64;
      int rr = ch >> 3, cc = ch & 7;
      short8 v = *(const short8*)(cs + rr * 64 + ((cc ^ (rr & 7)) * 8));
      *(short8*)&Cb[(size_t)(m0 + wm * 64 + rr) * ldc + n0 + wn * 64 + cc * 8] = v;
    }
  } else {
    float* cf = (float*)(void*)smem + w * 2048;
#pragma unroll
    for (int pass = 0; pass < 2; pass++) {
#pragma unroll
      for (int m2 = 0; m2 < 2; m2++)
#pragma unroll
        for (int ni = 0; ni < 4; ni++)
#pragma unroll
          for (int r = 0; r < 4; r++) {
            int row = m2 * 16 + quad * 4 + r;
            int ch  = ((ni * 4 + (l16 >> 2)) ^ (row & 15)) * 4 + (l16 & 3);
            cf[row * 64 + ch] = acc[pass * 2 + m2][ni][r] + bvv[ni];
          }
      float* Cf = (float*)C;
#pragma unroll
      for (int i = 0; i < 8; i++) {
        int ch = lane + i * 64;
        int rr = ch >> 4, cc = ch & 15;
        f32x4 v = *(const f32x4*)(cf + rr * 64 + ((cc ^ (rr & 15)) * 4));
        *(f32x4*)&Cf[(size_t)(m0 + wm * 64 + pass * 32 + rr) * ldc +
                     n0 + wn * 64 + cc * 4] = v;
      }
    }
  }
}

// ---------------------------------------------------------------------------
// Causal flash attention, swapped 32x32 QK^T + in-register softmax (T12).
// Adjacent pairs (2j,2j+1), heavy-first; packed layout qcol=64+h*48,
// kcol=832+h*48; V from Vt (fused GEMM epilogue). Triple-buffer + counted
// vmcnt(4). Unchanged from round 9.
// ---------------------------------------------------------------------------
__global__ __launch_bounds__(256, 3) void attn_kernel(
    const u16* __restrict__ P, const u16* __restrict__ Vt,
    u16* __restrict__ Y)
{
  const int bh  = blockIdx.x;
  const int b   = bh >> 4, h = bh & 15;
  const int j   = 15 - blockIdx.y;      // heavy-first
  const int qtA = 2 * j, qtB = 2 * j + 1;
  const int tid = threadIdx.x;
  const int w   = tid >> 6;
  const int lane = tid & 63;
  const int l32 = lane & 31, hi = lane >> 5;
  const size_t rowb = (size_t)b * SEQ_T;
  const int qcol = QOFF + h * PRIV;
  const int kcol = KOFF + h * PRIV;

  __shared__ __align__(16) u16 Ks[3][64 * 64];     // [j][dchunk^(j&7)]
  __shared__ __align__(16) u16 Vs[3][64 * 64];     // [d][tchunk^(d&7)]

  const float csc = 0.18033688011112042f;  // (1/8)*log2(e)
  const int iA = qtA * 64 + w * 16, iB = qtB * 64 + w * 16;
  // per-lane q: cols 0-15 = chain A, 16-31 = chain B
  const int gi = (l32 < 16) ? (iA + l32) : (iB + l32 - 16);
  const u16* qptr = P + (rowb + gi) * PNS;

  // Q B-frag: chunk c holds d = 16c + 8hi + e (e=0..7)
  short8 qb[4];
  qb[0] = *(const short8*)&qptr[8 * hi];                       // share d 0..15
#pragma unroll
  for (int c = 1; c < 4; c++)
    qb[c] = *(const short8*)&qptr[qcol + 16 * c + 8 * hi - 16];// priv d 16..63
#pragma unroll
  for (int c = 0; c < 4; c++)
#pragma unroll
    for (int e = 0; e < 8; e++)
      qb[c][e] = (short)f2bf(bf2f((u16)qb[c][e]) * csc);

  short8 ones;
#pragma unroll
  for (int e = 0; e < 8; e++) ones[e] = (short)0x3F80;

  const int nkt = qtB + 1;   // 2j+2: ranges 2..32

#if HAVE_GLL
#define GLOADA(g, l) gload_lds16((g), (l))
#else
#define GLOADA(g, l) (*(uint4*)(l) = *(const uint4*)(g))
#endif
#define STAGE_KV(t, bb)                                                        \
  {                                                                            \
    const int kk0 = (t) * 64;                                                  \
    _Pragma("unroll") for (int i2 = 0; i2 < 2; i2++) {                         \
      int c   = tid + i2 * 256;                                                \
      int row = c >> 3;                                                        \
      int dg  = ((c & 7) ^ (row & 7)) * 8;                                     \
      int col = (dg < 16) ? dg : (kcol + dg - 16);                             \
      GLOADA(&P[(rowb + kk0 + row) * PNS + col], &Ks[bb][c * 8]);              \
      GLOADA(&Vt[((size_t)bh * 64 + row) * SEQ_T + kk0 + dg], &Vs[bb][c * 8]); \
    }                                                                          \
  }

  f32x16 accy[2], accl;
#pragma unroll
  for (int r = 0; r < 16; r++) { accy[0][r] = 0.f; accy[1][r] = 0.f; accl[r] = 0.f; }

  const float ninf = -__builtin_inff();

  // prologue: tiles 0,1 in flight; confirm 0, leave 1 outstanding
  STAGE_KV(0, 0);
  STAGE_KV(1, 1);
  asm volatile("s_waitcnt vmcnt(4)" ::: "memory");
  __builtin_amdgcn_sched_barrier(0);
  __builtin_amdgcn_s_barrier();

  for (int kt = 0; kt < nkt; kt++) {
    const int cur = kt % 3;
    const int k0  = kt * 64;
    if (kt + 2 < nkt) STAGE_KV(kt + 2, (kt + 2) % 3);   // 2-deep prefetch

#pragma unroll
    for (int kk = 0; kk < 2; kk++) {
      // ---- S^T = K @ Q : C[key=(r&3)+8(r>>2)+4hi][q=l32] ----
      f32x16 s;
#pragma unroll
      for (int r = 0; r < 16; r++) s[r] = 0.f;
      const int krow = kk * 32 + l32;
      __builtin_amdgcn_s_setprio(1);
#pragma unroll
      for (int c = 0; c < 4; c++) {
        short8 ka = *(const short8*)&Ks[cur][krow * 64 + (((2 * c + hi) ^ (krow & 7)) * 8)];
        s = __builtin_amdgcn_mfma_f32_32x32x16_bf16(ka, qb[c], s, 0, 0, 0);
      }
      __builtin_amdgcn_s_setprio(0);

      // ---- causal mask ----
      if (kt == qtA || kt == qtB) {
#pragma unroll
        for (int r = 0; r < 16; r++) {
          int gj = k0 + kk * 32 + (r & 3) + 8 * (r >> 2) + 4 * hi;
          if (gj > gi) s[r] = ninf;
        }
      }
      if (kt > qtA) {   // chain-A cols fully masked past their diagonal (1 iter)
#pragma unroll
        for (int r = 0; r < 16; r++)
          if (l32 < 16) s[r] = ninf;
      }

      // ---- p = exp2(s) ----
      float px[16];
#pragma unroll
      for (int r = 0; r < 16; r++) px[r] = EXP2(s[r]);

      // ---- per 16-key chunk: in-register P->A-frag, then rowsum + PV ----
#pragma unroll
      for (int kc = 0; kc < 2; kc++) {
        unsigned g0, g1, g2, g3;
        asm("v_cvt_pk_bf16_f32 %0, %1, %2" : "=v"(g0) : "v"(px[8*kc+0]), "v"(px[8*kc+1]));
        asm("v_cvt_pk_bf16_f32 %0, %1, %2" : "=v"(g1) : "v"(px[8*kc+2]), "v"(px[8*kc+3]));
        asm("v_cvt_pk_bf16_f32 %0, %1, %2" : "=v"(g2) : "v"(px[8*kc+4]), "v"(px[8*kc+5]));
        asm("v_cvt_pk_bf16_f32 %0, %1, %2" : "=v"(g3) : "v"(px[8*kc+6]), "v"(px[8*kc+7]));
        // lane H holds keys {16kc+4H+m} in g0/g1 and {16kc+8+4H+m} in g2/g3.
        // A-frag lane hi needs keys 16kc+8hi+{0..7}: own half + partner half.
#if HAVE_PLSWAP
        uint2v r02 = __builtin_amdgcn_permlane32_swap(g0, g2, false, false);
        uint2v r13 = __builtin_amdgcn_permlane32_swap(g1, g3, false, false);
        uint32x4 pv = {r02.x, r13.x, r02.y, r13.y};
#else
        unsigned a0 = g0, b0 = g2, a1 = g1, b1 = g3;
        asm("v_permlane32_swap_b32 %0, %1" : "+v"(a0), "+v"(b0));
        asm("v_permlane32_swap_b32 %0, %1" : "+v"(a1), "+v"(b1));
        uint32x4 pv = {a0, a1, b0, b1};
#endif
        short8 pa = __builtin_bit_cast(short8, pv);

        __builtin_amdgcn_s_setprio(1);
        accl = __builtin_amdgcn_mfma_f32_32x32x16_bf16(pa, ones, accl, 0, 0, 0);
#pragma unroll
        for (int dt = 0; dt < 2; dt++) {
          int vrow = dt * 32 + l32;
          short8 vbf = *(const short8*)&Vs[cur][vrow * 64 + (((4*kk + 2*kc + hi) ^ (vrow & 7)) * 8)];
          accy[dt] = __builtin_amdgcn_mfma_f32_32x32x16_bf16(pa, vbf, accy[dt], 0, 0, 0);
        }
        __builtin_amdgcn_s_setprio(0);
      }
    }

    // counted bottom wait: keep next-next tile's 4 loads in flight
    if (kt + 3 < nkt) {
      asm volatile("s_waitcnt vmcnt(4)" ::: "memory");
      __builtin_amdgcn_sched_barrier(0);
      __builtin_amdgcn_s_barrier();
    } else if (kt + 2 == nkt) {       // kt == nkt-2: drain the last tile
      asm volatile("s_waitcnt vmcnt(0)" ::: "memory");
      __builtin_amdgcn_sched_barrier(0);
      __builtin_amdgcn_s_barrier();
    } else if (kt + 3 == nkt) {       // kt == nkt-3: confirm tile nkt-2
      asm volatile("s_waitcnt vmcnt(4)" ::: "memory");
      __builtin_amdgcn_sched_barrier(0);
      __builtin_amdgcn_s_barrier();
    }
    // kt == nkt-1: no wait, fall through to epilogue
  }
#undef STAGE_KV
#undef GLOADA

  // ---- epilogue: C[row=q][col=d]; q=(r&3)+8(r>>2)+4hi; r<8 -> chain A ----
  float inv[16];
#pragma unroll
  for (int r = 0; r < 16; r++) inv[r] = 1.0f / accl[r];
#pragma unroll
  for (int r = 0; r < 16; r++) {
    int q = (r & 3) + 8 * (r >> 2) + 4 * hi;
    int grow = (r < 8) ? (iA + q) : (iB + q - 16);
    size_t base = (rowb + grow) * N_EMBD + h * HEAD_DIM + l32;
    Y[base]      = f2bf(accy[0][r] * inv[r]);
    Y[base + 32] = f2bf(accy[1][r] * inv[r]);
  }
}

// ---------------------------------------------------------------------------
extern "C" void kernel_launch(void* const* d_in, const int* in_sizes, int n_in,
                              void* d_out, int out_size, void* d_ws, size_t ws_size,
                              hipStream_t stream) {
  (void)in_sizes; (void)n_in; (void)out_size; (void)ws_size;
  const void* x   = d_in[0];
  const void* Wsh = d_in[1];
  const void* bsh = d_in[2];
  const void* Wq  = d_in[3];
  const void* bq  = d_in[4];
  const void* Wk  = d_in[5];
  const void* bk  = d_in[6];
  const void* Wv  = d_in[7];
  const void* bv  = d_in[8];
  const void* Wo  = d_in[9];
  const void* bo  = d_in[10];

  char* wsb = (char*)d_ws;
  int* flag = (int*)wsb;
  u16* ws16 = (u16*)(wsb + 64);
  u16* Wcat = ws16;                                   // PNS*1024 (transposed)
  u16* bcat = Wcat + (size_t)PNS * N_EMBD;            // PNS
  u16* Woc  = bcat + PNS;                             // 1024*1024 (transposed)
  u16* boc  = Woc + (size_t)N_EMBD * N_EMBD;          // 1024
  u16* Pb   = boc + N_EMBD;                           // 8192*2816
  u16* Yb   = Pb + (size_t)M_ROWS * PNS;              // 8192*1024 (also Xb)
  u16* Vtb  = Yb + (size_t)M_ROWS * N_EMBD;           // 64*64*2048
  u16* Xb   = Yb;   // x->bf16 staging aliases Yb: proj reads Xb, attn writes Yb later

  detect_kernel<<<dim3(1), dim3(256), 0, stream>>>((const u16*)x, flag);
  // pack (z=0..5) + merged x->bf16 (z=6), concurrent
  pack_t_kernel<<<dim3(16, 16, 7), dim3(256), 0, stream>>>(
      Wsh, Wq, Wk, Wv, Wo, bsh, bq, bk, bv, bo, Wcat, Woc, bcat, boc,
      x, Xb, flag);
  // proj GEMM: [8192 x 2816] = Xb @ Wcat^T, bf16 out; V block -> Vtb transposed
  gemm8p_kernel<<<dim3(64 * (PNS / 256)), dim3(512), 0, stream>>>(
      Xb, Wcat, bcat, Pb, PNS, 64, flag, 0, Vtb, 1);
  attn_kernel<<<dim3(BATCH * N_HEADS, NTILES / 2), dim3(256), 0, stream>>>(
      Pb, Vtb, Yb);
  // out GEMM: [8192 x 1024] = Yb @ Woc^T, f32 out when inputs were f32
  gemm8p_kernel<<<dim3(64 * (N_EMBD / 256)), dim3(512), 0, stream>>>(
      Yb, Woc, boc, d_out, N_EMBD, 64, flag, 1, nullptr, 0);
}

// Round 11
// 247.774 us; speedup vs baseline: 1.2128x; 1.0421x over previous
//
#include <hip/hip_runtime.h>
#include <hip/hip_bf16.h>

typedef unsigned short u16;
typedef short short8 __attribute__((ext_vector_type(8)));
typedef float f32x4 __attribute__((ext_vector_type(4)));
typedef float f32x16 __attribute__((ext_vector_type(16)));
typedef unsigned uint32x4 __attribute__((ext_vector_type(4)));

#define N_EMBD   1024
#define N_HEADS  16
#define HEAD_DIM 64
#define PRIV     48
#define SEQ_T    2048
#define BATCH    4
#define M_ROWS   (BATCH*SEQ_T)   // 8192
// Packed proj layout: [share 16 | pad 48 | q 768 | k 768 | v 1024 | pad]
//   share@0, q@64, k@832, v@1600 (64-ALIGNED so one GEMM wave = one head), end 2624 -> pad to 2816.
#define PNS      2816
#define QOFF     64
#define KOFF     832
#define VOFF     1600
#define NTILES   (SEQ_T/64)      // 32
#define NT_K     16              // K=1024 / BK=64

#if __has_builtin(__builtin_amdgcn_exp2f)
#define EXP2(x) __builtin_amdgcn_exp2f(x)
#else
#define EXP2(x) exp2f(x)
#endif

#if __has_builtin(__builtin_amdgcn_global_load_lds)
#define HAVE_GLL 1
#else
#define HAVE_GLL 0
#endif

#if __has_builtin(__builtin_amdgcn_permlane32_swap)
#define HAVE_PLSWAP 1
typedef unsigned uint2v __attribute__((ext_vector_type(2)));
#else
#define HAVE_PLSWAP 0
#endif

__device__ __forceinline__ u16 f2bf(float f) {
  __hip_bfloat16 h = __float2bfloat16(f);
  return *reinterpret_cast<u16*>(&h);
}
__device__ __forceinline__ float bf2f(u16 s) {
  __hip_bfloat16 h;
  *reinterpret_cast<u16*>(&h) = s;
  return __bfloat162float(h);
}
__device__ __forceinline__ float loadv(const void* p, size_t i, int isf32) {
  return isf32 ? ((const float*)p)[i] : bf2f(((const u16*)p)[i]);
}
__device__ __forceinline__ u16 truncbf(float f) {
  unsigned u = __builtin_bit_cast(unsigned, f);
  return (u16)(u >> 16);
}
#if HAVE_GLL
__device__ __forceinline__ void gload_lds16(const u16* g, u16* l) {
  __builtin_amdgcn_global_load_lds(
      (const __attribute__((address_space(1))) void*)g,
      (__attribute__((address_space(3))) void*)l, 16, 0, 0);
}
#endif

// ---------------------------------------------------------------------------
// Transposing pack (weights -> [n][k] bf16); z=5 pad+biases+flag-write; z=6 =
// merged x->bf16. ROUND 11: detect_kernel deleted -- every pack block
// SELF-DETECTS the dtype from x[0..511] (1KB, L2-cached, block-local count);
// the z=5/flat==0 block persists the flag for the downstream GEMMs.
// ---------------------------------------------------------------------------
__global__ __launch_bounds__(256) void pack_t_kernel(
    const void* __restrict__ Wsh, const void* __restrict__ Wq,
    const void* __restrict__ Wk,  const void* __restrict__ Wv,
    const void* __restrict__ Wo,
    const void* __restrict__ bsh, const void* __restrict__ bq,
    const void* __restrict__ bk,  const void* __restrict__ bv,
    const void* __restrict__ bo,
    u16* __restrict__ Wcat, u16* __restrict__ Woc,
    u16* __restrict__ bcat, u16* __restrict__ boc,
    const void* __restrict__ x, u16* __restrict__ Xb,
    int* __restrict__ flagp)
{
  // ---- self-detect dtype (replicates old detect_kernel per-block) ----
  __shared__ int cnt_sm;
  if (threadIdx.x == 0) cnt_sm = 0;
  __syncthreads();
  {
    u16 v = ((const u16*)x)[2 * threadIdx.x];
    int e = (v >> 7) & 0xFF;
    if (e >= 0xC0 || (e != 0 && e <= 0x30)) atomicAdd(&cnt_sm, 1);
  }
  __syncthreads();
  const int f = (cnt_sm > 16) ? 1 : 0;

  if (blockIdx.z == 6) {  // merged x -> bf16 (8192x1024, 8 elems/group)
    const int flat = blockIdx.y * 16 + blockIdx.x;   // 0..255
#pragma unroll
    for (int it = 0; it < 16; it++) {
      size_t i = (size_t)flat * 4096 + it * 256 + threadIdx.x;
      if (f) {
        const float4* p = (const float4*)x;
        float4 a = p[i * 2], b = p[i * 2 + 1];
        u16 t[8] = {f2bf(a.x), f2bf(a.y), f2bf(a.z), f2bf(a.w),
                    f2bf(b.x), f2bf(b.y), f2bf(b.z), f2bf(b.w)};
        *(uint4*)&Xb[i * 8] = *(const uint4*)t;
      } else {
        *(uint4*)&Xb[i * 8] = ((const uint4*)x)[i];
      }
    }
    return;
  }
  if (blockIdx.z == 5) {  // pad + biases + flag persist
    const int flat = blockIdx.y * 16 + blockIdx.x;
    const int padRows = 48 + 192;   // rows 16..63 and 2624..2815
    for (int i = flat * 256 + threadIdx.x; i < padRows * 1024; i += 256 * 256) {
      int r = i >> 10, c2 = i & 1023;
      int row = (r < 48) ? (16 + r) : (2624 + (r - 48));
      Wcat[(size_t)row * 1024 + c2] = 0;
    }
    if (flat == 0) {
      if (threadIdx.x == 0) *flagp = f;   // GEMMs read this
      for (int c = threadIdx.x; c < PNS; c += 256) {
        float v = 0.f;
        if (c < 16)         v = loadv(bsh, c, f);
        else if (c < QOFF)  v = 0.f;
        else if (c < KOFF)  v = loadv(bq, c - QOFF, f);
        else if (c < VOFF)  v = loadv(bk, c - KOFF, f);
        else if (c < 2624)  v = loadv(bv, c - VOFF, f);
        bcat[c] = f2bf(v);
      }
    } else if (flat == 1) {
      for (int c = threadIdx.x; c < N_EMBD; c += 256)
        boc[c] = f2bf(loadv(bo, c, f));
    }
    return;
  }
  const void* src; u16* dst; int N, rowOff;
  switch (blockIdx.z) {
    case 0: src = Wsh; dst = Wcat; N = 16;   rowOff = 0;    break;
    case 1: src = Wq;  dst = Wcat; N = 768;  rowOff = QOFF; break;
    case 2: src = Wk;  dst = Wcat; N = 768;  rowOff = KOFF; break;
    case 3: src = Wv;  dst = Wcat; N = 1024; rowOff = VOFF; break;
    default:src = Wo;  dst = Woc;  N = 1024; rowOff = 0;    break;
  }
  const int n0 = blockIdx.x * 64;
  if (n0 >= N) return;
  const int k0 = blockIdx.y * 64;
  __shared__ u16 t[64][65];
  const int tx = threadIdx.x & 63, ty = threadIdx.x >> 6;
#pragma unroll
  for (int rr = 0; rr < 16; rr++) {
    int k = k0 + ty * 16 + rr;
    int n = n0 + tx;
    float v = (n < N) ? loadv(src, (size_t)k * N + n, f) : 0.f;
    t[ty * 16 + rr][tx] = f2bf(v);
  }
  __syncthreads();
#pragma unroll
  for (int rr = 0; rr < 16; rr++) {
    int n = ty * 16 + rr;
    if (n0 + n < N)
      dst[(size_t)(rowOff + n0 + n) * 1024 + k0 + tx] = t[tx][n];
  }
}

// ---------------------------------------------------------------------------
// 8-wave deep-pipelined bf16 GEMM: C(MxN) = A(MxK=1024) @ Bt(NxK)^T + bias.
// Tile BM=128 x BN=256, BK=64. Triple-buffered LDS; counted vmcnt(6) (T3+T4);
// T2 XOR swizzle; T5 setprio. Fused V-transpose epilogue (round 9).
// L2-locality tile mapping (round 10): xcd owns an 8-row A-strip (2MB,
// L2-resident), sweeps B-panels: mb = xcd*8 + (s&7), nb = s>>3.
// ROUND 11: waves whose 64-col slice is entirely pad (ncol0 >= 2624, proj
// only) skip their stores -- nothing reads those columns.
// ---------------------------------------------------------------------------
__global__ __launch_bounds__(512, 2) void gemm8p_kernel(
    const u16* __restrict__ A,    // [M][1024] bf16
    const u16* __restrict__ Bt,   // [N][1024] bf16
    const u16* __restrict__ bias, // [N] bf16
    void* __restrict__ C, int ldc, int Mtiles,
    const int* __restrict__ flagp, int c_dyn,
    u16* __restrict__ VtOut, int vt_en)
{
  (void)Mtiles;
  __shared__ __align__(16) u16 smem[73728];   // 147456 B
  u16* const As = smem;                       // 3 x [128*64]
  u16* const Bs = smem + 3 * 8192;            // 3 x [256*64]

  const bool cf32 = (c_dyn != 0) && (*flagp != 0);

  const int tid  = threadIdx.x;
  const int lane = tid & 63;
  const int w    = tid >> 6;
  const int quad = lane >> 4, l16 = lane & 15;
  const int wm   = w >> 2, wn = w & 3;

  const int xcd = blockIdx.x & 7;
  const int s   = blockIdx.x >> 3;
  const int mb  = xcd * 8 + (s & 7);
  const int nb  = s >> 3;
  const int m0  = mb * 128, n0 = nb * 256;

  int ldsA[2]; size_t glA[2];
  int ldsB[2][2]; size_t glB[2][2];
#pragma unroll
  for (int rd = 0; rd < 2; rd++) {
    int j = tid + rd * 512, rp = j >> 3, sl = j & 7;
    int cl = (sl ^ (rp & 7)) * 8;
    ldsA[rd] = rp * 64 + sl * 8;
    glA[rd]  = (size_t)(m0 + rp) * 1024 + cl;
#pragma unroll
    for (int nh = 0; nh < 2; nh++) {
      int cc = (rp & 31) + nh * 32 + (rp >> 5) * 64;
      ldsB[nh][rd] = cc * 64 + sl * 8;
      glB[nh][rd]  = (size_t)(n0 + cc) * 1024 + cl;
    }
  }

#if HAVE_GLL
#define G8(g, l) gload_lds16((g), (l))
#else
#define G8(g, l) (*(uint4*)(l) = *(const uint4*)(g))
#endif
#define STG_A(t, bf)                                                       \
  if ((t) < NT_K) {                                                        \
    _Pragma("unroll") for (int rd = 0; rd < 2; rd++)                       \
      G8(A + glA[rd] + (t) * 64, As + (bf) * 8192 + ldsA[rd]);             \
  }
#define STG_B(nh, t, bf)                                                   \
  if ((t) < NT_K) {                                                        \
    _Pragma("unroll") for (int rd = 0; rd < 2; rd++)                       \
      G8(Bt + glB[nh][rd] + (t) * 64, Bs + (bf) * 16384 + ldsB[nh][rd]);   \
  }

  const int ck0  = ((quad)     ^ (l16 & 7)) * 8;
  const int ck1  = ((4 + quad) ^ (l16 & 7)) * 8;
  const int arow = (wm * 64 + l16) * 64;
  const int brow = (wn * 64 + l16) * 64;

  f32x4 acc[4][4];
#pragma unroll
  for (int i = 0; i < 4; i++)
#pragma unroll
    for (int j = 0; j < 4; j++) acc[i][j] = (f32x4){0.f, 0.f, 0.f, 0.f};

  short8 af[4][2], bA[2][2], bB[2][2];

#define READ_A(cur)                                                        \
  { const u16* pa = As + (cur) * 8192 + arow;                              \
    _Pragma("unroll") for (int m = 0; m < 4; m++) {                        \
      af[m][0] = *(const short8*)(pa + m * 1024 + ck0);                    \
      af[m][1] = *(const short8*)(pa + m * 1024 + ck1); } }
#define READ_B(dst, nh, cur)                                               \
  { const u16* pb = Bs + (cur) * 16384 + brow + (nh) * 2048;               \
    _Pragma("unroll") for (int n = 0; n < 2; n++) {                        \
      dst[n][0] = *(const short8*)(pb + n * 1024 + ck0);                   \
      dst[n][1] = *(const short8*)(pb + n * 1024 + ck1); } }
#define MM16(bfr, nh)                                                      \
  __builtin_amdgcn_s_setprio(1);                                           \
  _Pragma("unroll") for (int m = 0; m < 4; m++)                            \
    _Pragma("unroll") for (int n = 0; n < 2; n++) {                        \
      acc[m][(nh)*2+n] = __builtin_amdgcn_mfma_f32_16x16x32_bf16(          \
          af[m][0], bfr[n][0], acc[m][(nh)*2+n], 0, 0, 0);                 \
      acc[m][(nh)*2+n] = __builtin_amdgcn_mfma_f32_16x16x32_bf16(          \
          af[m][1], bfr[n][1], acc[m][(nh)*2+n], 0, 0, 0); }               \
  __builtin_amdgcn_s_setprio(0);
#define BARR { __builtin_amdgcn_s_barrier(); __builtin_amdgcn_sched_barrier(0); }

  STG_A(0, 0); STG_B(1, 0, 0); STG_B(0, 0, 0);
  STG_A(1, 1); STG_B(1, 1, 1); STG_B(0, 1, 1);
  asm volatile("s_waitcnt vmcnt(6)");
  BARR;

#pragma unroll
  for (int kt = 0; kt < NT_K; kt++) {
    const int cur = kt % 3;
    const int stb = (kt + 2) % 3;
    READ_A(cur); READ_B(bA, 0, cur);
    STG_A(kt + 2, stb); STG_B(1, kt + 2, stb);
    BARR;
    MM16(bA, 0);
    BARR;
    READ_B(bB, 1, cur);
    STG_B(0, kt + 2, stb);
    BARR;
    MM16(bB, 1);
    if (kt < NT_K - 2)       { asm volatile("s_waitcnt vmcnt(6)"); }
    else if (kt == NT_K - 2) { asm volatile("s_waitcnt vmcnt(0)"); }
    BARR;
  }
#undef STG_A
#undef STG_B
#undef READ_A
#undef READ_B
#undef MM16
#undef BARR
#undef G8

  __syncthreads();   // cs slices overlap As/Bs buf0; make LDS reuse safe

  float bvv[4];
#pragma unroll
  for (int ni = 0; ni < 4; ni++)
    bvv[ni] = bf2f(bias[n0 + wn * 64 + ni * 16 + l16]);

  const int ncol0 = n0 + wn * 64;
  if (vt_en && ncol0 >= VOFF + 1024) return;   // pure-pad columns: no store
  if (vt_en && ncol0 >= VOFF) {
    // ---- fused V-transpose epilogue: acc -> cs_t[d][t] (swizzled) -> Vt ----
    u16* cs = smem + w * 4096;          // 64(d) x 64(t) bf16 per wave
#pragma unroll
    for (int m = 0; m < 4; m++)
#pragma unroll
      for (int ni = 0; ni < 4; ni++)
#pragma unroll
        for (int r = 0; r < 4; r++) {
          int d  = ni * 16 + l16;
          int tc = m * 2 + (quad >> 1);          // t>>3
          int te = (quad & 1) * 4 + r;           // t&7
          cs[d * 64 + ((tc ^ (d & 7)) * 8) + te] = f2bf(acc[m][ni][r] + bvv[ni]);
        }
    const int bb = (m0 + wm * 64) >> 11;
    const int t0 = (m0 + wm * 64) & 2047;
    const int hh = (ncol0 - VOFF) >> 6;
    __builtin_amdgcn_s_barrier();   // wave-local cs, but cheap ordering fence
#pragma unroll
    for (int i = 0; i < 8; i++) {
      int ch = lane + i * 64;
      int rr = ch >> 3, cc = ch & 7;   // rr = d, cc = t-chunk
      short8 v = *(const short8*)(cs + rr * 64 + ((cc ^ (rr & 7)) * 8));
      *(short8*)&VtOut[((size_t)(bb * 16 + hh) * 64 + rr) * SEQ_T + t0 + cc * 8] = v;
    }
  } else if (!cf32) {
    u16* cs = smem + w * 4096;
#pragma unroll
    for (int m = 0; m < 4; m++)
#pragma unroll
      for (int ni = 0; ni < 4; ni++)
#pragma unroll
        for (int r = 0; r < 4; r++) {
          int row = m * 16 + quad * 4 + r;
          int ch  = ((ni * 2 + (l16 >> 3)) ^ (row & 7)) * 8 + (l16 & 7);
          cs[row * 64 + ch] = f2bf(acc[m][ni][r] + bvv[ni]);
        }
    u16* Cb = (u16*)C;
#pragma unroll
    for (int i = 0; i < 8; i++) {
      int ch = lane + i * 64;
      int rr = ch >> 3, cc = ch & 7;
      short8 v = *(const short8*)(cs + rr * 64 + ((cc ^ (rr & 7)) * 8));
      *(short8*)&Cb[(size_t)(m0 + wm * 64 + rr) * ldc + n0 + wn * 64 + cc * 8] = v;
    }
  } else {
    float* cf = (float*)(void*)smem + w * 2048;
#pragma unroll
    for (int pass = 0; pass < 2; pass++) {
#pragma unroll
      for (int m2 = 0; m2 < 2; m2++)
#pragma unroll
        for (int ni = 0; ni < 4; ni++)
#pragma unroll
          for (int r = 0; r < 4; r++) {
            int row = m2 * 16 + quad * 4 + r;
            int ch  = ((ni * 4 + (l16 >> 2)) ^ (row & 15)) * 4 + (l16 & 3);
            cf[row * 64 + ch] = acc[pass * 2 + m2][ni][r] + bvv[ni];
          }
      float* Cf = (float*)C;
#pragma unroll
      for (int i = 0; i < 8; i++) {
        int ch = lane + i * 64;
        int rr = ch >> 4, cc = ch & 15;
        f32x4 v = *(const f32x4*)(cf + rr * 64 + ((cc ^ (rr & 15)) * 4));
        *(f32x4*)&Cf[(size_t)(m0 + wm * 64 + pass * 32 + rr) * ldc +
                     n0 + wn * 64 + cc * 4] = v;
      }
    }
  }
}

// ---------------------------------------------------------------------------
// Causal flash attention, swapped 32x32 QK^T + in-register softmax (T12).
// ROUND 11: VALU rowsum. The 4 per-iter mfma(pa, ones) rowsum MFMAs (20% of
// matrix work, on the serial pa path) are replaced by a 16-wide tree-sum of
// px per kk (32 VALU adds/iter): in the swapped layout each lane's px[] ARE
// its (q=l32, hi-half) probabilities. Full rowsum = vsum + shfl_xor(vsum,32)
// ONCE at the end; per-r divisor via one-time __shfl(invq, q(r)) broadcasts
// (both wave halves hold every q's total). accl + ones deleted (-20 VGPR).
// Adjacent pairs (2j,2j+1), heavy-first; triple-buffer + counted vmcnt(4).
// ---------------------------------------------------------------------------
__global__ __launch_bounds__(256, 3) void attn_kernel(
    const u16* __restrict__ P, const u16* __restrict__ Vt,
    u16* __restrict__ Y)
{
  const int bh  = blockIdx.x;
  const int b   = bh >> 4, h = bh & 15;
  const int j   = 15 - blockIdx.y;      // heavy-first
  const int qtA = 2 * j, qtB = 2 * j + 1;
  const int tid = threadIdx.x;
  const int w   = tid >> 6;
  const int lane = tid & 63;
  const int l32 = lane & 31, hi = lane >> 5;
  const size_t rowb = (size_t)b * SEQ_T;
  const int qcol = QOFF + h * PRIV;
  const int kcol = KOFF + h * PRIV;

  __shared__ __align__(16) u16 Ks[3][64 * 64];     // [j][dchunk^(j&7)]
  __shared__ __align__(16) u16 Vs[3][64 * 64];     // [d][tchunk^(d&7)]

  const float csc = 0.18033688011112042f;  // (1/8)*log2(e)
  const int iA = qtA * 64 + w * 16, iB = qtB * 64 + w * 16;
  // per-lane q: cols 0-15 = chain A, 16-31 = chain B
  const int gi = (l32 < 16) ? (iA + l32) : (iB + l32 - 16);
  const u16* qptr = P + (rowb + gi) * PNS;

  // Q B-frag: chunk c holds d = 16c + 8hi + e (e=0..7)
  short8 qb[4];
  qb[0] = *(const short8*)&qptr[8 * hi];                       // share d 0..15
#pragma unroll
  for (int c = 1; c < 4; c++)
    qb[c] = *(const short8*)&qptr[qcol + 16 * c + 8 * hi - 16];// priv d 16..63
#pragma unroll
  for (int c = 0; c < 4; c++)
#pragma unroll
    for (int e = 0; e < 8; e++)
      qb[c][e] = (short)f2bf(bf2f((u16)qb[c][e]) * csc);

  const int nkt = qtB + 1;   // 2j+2: ranges 2..32

#if HAVE_GLL
#define GLOADA(g, l) gload_lds16((g), (l))
#else
#define GLOADA(g, l) (*(uint4*)(l) = *(const uint4*)(g))
#endif
#define STAGE_KV(t, bb)                                                        \
  {                                                                            \
    const int kk0 = (t) * 64;                                                  \
    _Pragma("unroll") for (int i2 = 0; i2 < 2; i2++) {                         \
      int c   = tid + i2 * 256;                                                \
      int row = c >> 3;                                                        \
      int dg  = ((c & 7) ^ (row & 7)) * 8;                                     \
      int col = (dg < 16) ? dg : (kcol + dg - 16);                             \
      GLOADA(&P[(rowb + kk0 + row) * PNS + col], &Ks[bb][c * 8]);              \
      GLOADA(&Vt[((size_t)bh * 64 + row) * SEQ_T + kk0 + dg], &Vs[bb][c * 8]); \
    }                                                                          \
  }

  f32x16 accy[2];
#pragma unroll
  for (int r = 0; r < 16; r++) { accy[0][r] = 0.f; accy[1][r] = 0.f; }
  float vsum = 0.f;

  const float ninf = -__builtin_inff();

  // prologue: tiles 0,1 in flight; confirm 0, leave 1 outstanding
  STAGE_KV(0, 0);
  STAGE_KV(1, 1);
  asm volatile("s_waitcnt vmcnt(4)" ::: "memory");
  __builtin_amdgcn_sched_barrier(0);
  __builtin_amdgcn_s_barrier();

  for (int kt = 0; kt < nkt; kt++) {
    const int cur = kt % 3;
    const int k0  = kt * 64;
    if (kt + 2 < nkt) STAGE_KV(kt + 2, (kt + 2) % 3);   // 2-deep prefetch

#pragma unroll
    for (int kk = 0; kk < 2; kk++) {
      // ---- S^T = K @ Q : C[key=(r&3)+8(r>>2)+4hi][q=l32] ----
      f32x16 s;
#pragma unroll
      for (int r = 0; r < 16; r++) s[r] = 0.f;
      const int krow = kk * 32 + l32;
      __builtin_amdgcn_s_setprio(1);
#pragma unroll
      for (int c = 0; c < 4; c++) {
        short8 ka = *(const short8*)&Ks[cur][krow * 64 + (((2 * c + hi) ^ (krow & 7)) * 8)];
        s = __builtin_amdgcn_mfma_f32_32x32x16_bf16(ka, qb[c], s, 0, 0, 0);
      }
      __builtin_amdgcn_s_setprio(0);

      // ---- causal mask ----
      if (kt == qtA || kt == qtB) {
#pragma unroll
        for (int r = 0; r < 16; r++) {
          int gj = k0 + kk * 32 + (r & 3) + 8 * (r >> 2) + 4 * hi;
          if (gj > gi) s[r] = ninf;
        }
      }
      if (kt > qtA) {   // chain-A cols fully masked past their diagonal (1 iter)
#pragma unroll
        for (int r = 0; r < 16; r++)
          if (l32 < 16) s[r] = ninf;
      }

      // ---- p = exp2(s) ; rowsum on VALU (replaces ones-MFMA) ----
      float px[16];
#pragma unroll
      for (int r = 0; r < 16; r++) px[r] = EXP2(s[r]);
      vsum += (((px[0] + px[1]) + (px[2] + px[3])) +
               ((px[4] + px[5]) + (px[6] + px[7]))) +
              (((px[8] + px[9]) + (px[10] + px[11])) +
               ((px[12] + px[13]) + (px[14] + px[15])));

      // ---- per 16-key chunk: in-register P->A-frag, then PV ----
#pragma unroll
      for (int kc = 0; kc < 2; kc++) {
        unsigned g0, g1, g2, g3;
        asm("v_cvt_pk_bf16_f32 %0, %1, %2" : "=v"(g0) : "v"(px[8*kc+0]), "v"(px[8*kc+1]));
        asm("v_cvt_pk_bf16_f32 %0, %1, %2" : "=v"(g1) : "v"(px[8*kc+2]), "v"(px[8*kc+3]));
        asm("v_cvt_pk_bf16_f32 %0, %1, %2" : "=v"(g2) : "v"(px[8*kc+4]), "v"(px[8*kc+5]));
        asm("v_cvt_pk_bf16_f32 %0, %1, %2" : "=v"(g3) : "v"(px[8*kc+6]), "v"(px[8*kc+7]));
        // lane H holds keys {16kc+4H+m} in g0/g1 and {16kc+8+4H+m} in g2/g3.
        // A-frag lane hi needs keys 16kc+8hi+{0..7}: own half + partner half.
#if HAVE_PLSWAP
        uint2v r02 = __builtin_amdgcn_permlane32_swap(g0, g2, false, false);
        uint2v r13 = __builtin_amdgcn_permlane32_swap(g1, g3, false, false);
        uint32x4 pv = {r02.x, r13.x, r02.y, r13.y};
#else
        unsigned a0 = g0, b0 = g2, a1 = g1, b1 = g3;
        asm("v_permlane32_swap_b32 %0, %1" : "+v"(a0), "+v"(b0));
        asm("v_permlane32_swap_b32 %0, %1" : "+v"(a1), "+v"(b1));
        uint32x4 pv = {a0, a1, b0, b1};
#endif
        short8 pa = __builtin_bit_cast(short8, pv);

        __builtin_amdgcn_s_setprio(1);
#pragma unroll
        for (int dt = 0; dt < 2; dt++) {
          int vrow = dt * 32 + l32;
          short8 vbf = *(const short8*)&Vs[cur][vrow * 64 + (((4*kk + 2*kc + hi) ^ (vrow & 7)) * 8)];
          accy[dt] = __builtin_amdgcn_mfma_f32_32x32x16_bf16(pa, vbf, accy[dt], 0, 0, 0);
        }
        __builtin_amdgcn_s_setprio(0);
      }
    }

    // counted bottom wait: keep next-next tile's 4 loads in flight
    if (kt + 3 < nkt) {
      asm volatile("s_waitcnt vmcnt(4)" ::: "memory");
      __builtin_amdgcn_sched_barrier(0);
      __builtin_amdgcn_s_barrier();
    } else if (kt + 2 == nkt) {       // kt == nkt-2: drain the last tile
      asm volatile("s_waitcnt vmcnt(0)" ::: "memory");
      __builtin_amdgcn_sched_barrier(0);
      __builtin_amdgcn_s_barrier();
    } else if (kt + 3 == nkt) {       // kt == nkt-3: confirm tile nkt-2
      asm volatile("s_waitcnt vmcnt(4)" ::: "memory");
      __builtin_amdgcn_sched_barrier(0);
      __builtin_amdgcn_s_barrier();
    }
    // kt == nkt-1: no wait, fall through to epilogue
  }
#undef STAGE_KV
#undef GLOADA

  // ---- epilogue ----
  // full rowsum for q=l32: own half + partner half (one-time cross-lane op)
  float tot  = vsum + __shfl_xor(vsum, 32);
  float invq = 1.0f / tot;
  // C[row=q][col=d]; q=(r&3)+8(r>>2)+4hi; r<8 -> chain A
#pragma unroll
  for (int r = 0; r < 16; r++) {
    int q = (r & 3) + 8 * (r >> 2) + 4 * hi;
    float iv = __shfl(invq, q);      // lane q (<32) holds q's total; broadcast
    int grow = (r < 8) ? (iA + q) : (iB + q - 16);
    size_t base = (rowb + grow) * N_EMBD + h * HEAD_DIM + l32;
    Y[base]      = f2bf(accy[0][r] * iv);
    Y[base + 32] = f2bf(accy[1][r] * iv);
  }
}

// ---------------------------------------------------------------------------
extern "C" void kernel_launch(void* const* d_in, const int* in_sizes, int n_in,
                              void* d_out, int out_size, void* d_ws, size_t ws_size,
                              hipStream_t stream) {
  (void)in_sizes; (void)n_in; (void)out_size; (void)ws_size;
  const void* x   = d_in[0];
  const void* Wsh = d_in[1];
  const void* bsh = d_in[2];
  const void* Wq  = d_in[3];
  const void* bq  = d_in[4];
  const void* Wk  = d_in[5];
  const void* bk  = d_in[6];
  const void* Wv  = d_in[7];
  const void* bv  = d_in[8];
  const void* Wo  = d_in[9];
  const void* bo  = d_in[10];

  char* wsb = (char*)d_ws;
  int* flag = (int*)wsb;
  u16* ws16 = (u16*)(wsb + 64);
  u16* Wcat = ws16;                                   // PNS*1024 (transposed)
  u16* bcat = Wcat + (size_t)PNS * N_EMBD;            // PNS
  u16* Woc  = bcat + PNS;                             // 1024*1024 (transposed)
  u16* boc  = Woc + (size_t)N_EMBD * N_EMBD;          // 1024
  u16* Pb   = boc + N_EMBD;                           // 8192*2816
  u16* Yb   = Pb + (size_t)M_ROWS * PNS;              // 8192*1024 (also Xb)
  u16* Vtb  = Yb + (size_t)M_ROWS * N_EMBD;           // 64*64*2048
  u16* Xb   = Yb;   // x->bf16 staging aliases Yb: proj reads Xb, attn writes Yb later

  // pack (z=0..5) + merged x->bf16 (z=6); blocks self-detect dtype, z=5/flat0
  // writes the flag for the GEMMs. (detect_kernel deleted, round 11)
  pack_t_kernel<<<dim3(16, 16, 7), dim3(256), 0, stream>>>(
      Wsh, Wq, Wk, Wv, Wo, bsh, bq, bk, bv, bo, Wcat, Woc, bcat, boc,
      x, Xb, flag);
  // proj GEMM: [8192 x 2816] = Xb @ Wcat^T, bf16 out; V block -> Vtb transposed
  gemm8p_kernel<<<dim3(64 * (PNS / 256)), dim3(512), 0, stream>>>(
      Xb, Wcat, bcat, Pb, PNS, 64, flag, 0, Vtb, 1);
  attn_kernel<<<dim3(BATCH * N_HEADS, NTILES / 2), dim3(256), 0, stream>>>(
      Pb, Vtb, Yb);
  // out GEMM: [8192 x 1024] = Yb @ Woc^T, f32 out when inputs were f32
  gemm8p_kernel<<<dim3(64 * (N_EMBD / 256)), dim3(512), 0, stream>>>(
      Yb, Woc, boc, d_out, N_EMBD, 64, flag, 1, nullptr, 0);
}